// Round 1
// baseline (654.217 us; speedup 1.0000x reference)
//
#include <hip/hip_runtime.h>
#include <hip/hip_bf16.h>
#include <math.h>

// ---------------------------------------------------------------------------
// GCNEncoderWithGate: h = x*sigmoid(x@gW+gb); 2x { g=(h@W)*dinv; out[d]=dinv[d]*(sum g[src]+g[d])+b }
// Strategy: CSR build once (dst shared by both layers), gather-based SpMM (no fp32 atomics),
// fp32 register-tiled GEMM with W + A-rows staged in LDS.
// ---------------------------------------------------------------------------

__global__ void deg_kernel(const int* __restrict__ dst, int* __restrict__ deg, int E) {
    int e = blockIdx.x * blockDim.x + threadIdx.x;
    if (e < E) atomicAdd(&deg[dst[e]], 1);
}

__global__ void dinv_kernel(const int* __restrict__ deg, float* __restrict__ dinv, int n) {
    int i = blockIdx.x * blockDim.x + threadIdx.x;
    if (i < n) dinv[i] = rsqrtf((float)(deg[i] + 1));  // +1 = self loop
}

// pass1: sum each 1024-element chunk of deg
__global__ void chunk_sum_kernel(const int* __restrict__ deg, int* __restrict__ bsum, int n) {
    int b = blockIdx.x, t = threadIdx.x;
    int base = b * 1024 + t * 4;
    int s = 0;
#pragma unroll
    for (int j = 0; j < 4; j++) { int idx = base + j; if (idx < n) s += deg[idx]; }
    for (int off = 32; off > 0; off >>= 1) s += __shfl_down(s, off, 64);
    __shared__ int ws[4];
    int lane = t & 63, w = t >> 6;
    if (lane == 0) ws[w] = s;
    __syncthreads();
    if (t == 0) bsum[b] = ws[0] + ws[1] + ws[2] + ws[3];
}

// pass2: exclusive scan of chunk sums (nc <= 1024); writes rowptr[n] = total
__global__ void chunk_scan_kernel(const int* __restrict__ bsum, int* __restrict__ cbase,
                                  int* __restrict__ rowptr, int nc, int n) {
    __shared__ int sm[1024];
    int t = threadIdx.x;
    int v = (t < nc) ? bsum[t] : 0;
    sm[t] = v;
    __syncthreads();
    for (int off = 1; off < 1024; off <<= 1) {
        int add = (t >= off) ? sm[t - off] : 0;
        __syncthreads();
        sm[t] += add;
        __syncthreads();
    }
    if (t < nc) cbase[t] = sm[t] - v;
    if (t == 0) rowptr[n] = sm[1023];
}

// pass3: per-chunk exclusive scan -> rowptr & cursor
__global__ void scan_write_kernel(const int* __restrict__ deg, const int* __restrict__ cbase,
                                  int* __restrict__ rowptr, int* __restrict__ cursor, int n) {
    int b = blockIdx.x, t = threadIdx.x;
    int base = b * 1024 + t * 4;
    int d0 = 0, d1 = 0, d2 = 0, d3 = 0;
    if (base + 0 < n) d0 = deg[base + 0];
    if (base + 1 < n) d1 = deg[base + 1];
    if (base + 2 < n) d2 = deg[base + 2];
    if (base + 3 < n) d3 = deg[base + 3];
    int tsum = d0 + d1 + d2 + d3;
    int v = tsum;
    int lane = t & 63;
    for (int off = 1; off < 64; off <<= 1) {
        int u = __shfl_up(v, off, 64);
        if (lane >= off) v += u;
    }
    __shared__ int wsum[4];
    int w = t >> 6;
    if (lane == 63) wsum[w] = v;
    __syncthreads();
    int wb = 0;
#pragma unroll
    for (int j = 0; j < 4; j++) if (j < w) wb += wsum[j];
    int excl = cbase[b] + wb + (v - tsum);
    int e0 = excl, e1 = e0 + d0, e2 = e1 + d1, e3 = e2 + d2;
    if (base + 0 < n) { rowptr[base + 0] = e0; cursor[base + 0] = e0; }
    if (base + 1 < n) { rowptr[base + 1] = e1; cursor[base + 1] = e1; }
    if (base + 2 < n) { rowptr[base + 2] = e2; cursor[base + 2] = e2; }
    if (base + 3 < n) { rowptr[base + 3] = e3; cursor[base + 3] = e3; }
}

__global__ void fill_kernel(const int* __restrict__ src, const int* __restrict__ dst,
                            int* __restrict__ cursor, int* __restrict__ col, int E) {
    int e = blockIdx.x * blockDim.x + threadIdx.x;
    if (e < E) {
        int d = dst[e];
        int p = atomicAdd(&cursor[d], 1);
        col[p] = src[e];
    }
}

// ---------------------------------------------------------------------------
// GEMM: out[row,:] = epilogue(A[row,:] @ W)
// MODE 0: out = A * sigmoid(A@W + bias)          (bias_or_dinv = gate_b[128])
// MODE 1: out = (A@W) * dinv[row]                (bias_or_dinv = dinv[N])
// Block: 512 threads, 64 rows. Thread = 4 rows x 4 cols register tile.
// LDS: W 64KB + Xl 64x132 (pad 4 -> float4-aligned rows, conflict-free)
// ---------------------------------------------------------------------------
template <int MODE>
__launch_bounds__(512, 1)
__global__ void gemm_kernel(const float* __restrict__ A, const float* __restrict__ W,
                            const float* __restrict__ bias_or_dinv, float* __restrict__ out,
                            int n) {
    __shared__ float Wl[128][128];
    __shared__ float Xl[64][132];
    int t = threadIdx.x;

    const float4* W4 = (const float4*)W;
    float4* Wl4 = (float4*)&Wl[0][0];
#pragma unroll
    for (int i = t; i < 4096; i += 512) Wl4[i] = W4[i];

    int row0 = blockIdx.x * 64;
    for (int i = t; i < 2048; i += 512) {
        int r = i >> 5, c4 = i & 31;
        int row = row0 + r;
        float4 v = make_float4(0.f, 0.f, 0.f, 0.f);
        if (row < n) v = *(const float4*)&A[(size_t)row * 128 + c4 * 4];
        *(float4*)&Xl[r][c4 * 4] = v;
    }
    __syncthreads();

    int cg = t & 31;   // col group: cols 4*cg .. 4*cg+3
    int rg = t >> 5;   // row group: rows 4*rg .. 4*rg+3 (local)
    float acc[4][4];
#pragma unroll
    for (int a = 0; a < 4; a++)
#pragma unroll
        for (int b = 0; b < 4; b++) acc[a][b] = 0.f;

    for (int k = 0; k < 128; k += 4) {
        float4 w0 = *(float4*)&Wl[k + 0][cg * 4];
        float4 w1 = *(float4*)&Wl[k + 1][cg * 4];
        float4 w2 = *(float4*)&Wl[k + 2][cg * 4];
        float4 w3 = *(float4*)&Wl[k + 3][cg * 4];
#pragma unroll
        for (int rr = 0; rr < 4; rr++) {
            float4 xv = *(float4*)&Xl[rg * 4 + rr][k];
            acc[rr][0] = fmaf(xv.x, w0.x, acc[rr][0]);
            acc[rr][1] = fmaf(xv.x, w0.y, acc[rr][1]);
            acc[rr][2] = fmaf(xv.x, w0.z, acc[rr][2]);
            acc[rr][3] = fmaf(xv.x, w0.w, acc[rr][3]);
            acc[rr][0] = fmaf(xv.y, w1.x, acc[rr][0]);
            acc[rr][1] = fmaf(xv.y, w1.y, acc[rr][1]);
            acc[rr][2] = fmaf(xv.y, w1.z, acc[rr][2]);
            acc[rr][3] = fmaf(xv.y, w1.w, acc[rr][3]);
            acc[rr][0] = fmaf(xv.z, w2.x, acc[rr][0]);
            acc[rr][1] = fmaf(xv.z, w2.y, acc[rr][1]);
            acc[rr][2] = fmaf(xv.z, w2.z, acc[rr][2]);
            acc[rr][3] = fmaf(xv.z, w2.w, acc[rr][3]);
            acc[rr][0] = fmaf(xv.w, w3.x, acc[rr][0]);
            acc[rr][1] = fmaf(xv.w, w3.y, acc[rr][1]);
            acc[rr][2] = fmaf(xv.w, w3.z, acc[rr][2]);
            acc[rr][3] = fmaf(xv.w, w3.w, acc[rr][3]);
        }
    }

#pragma unroll
    for (int rr = 0; rr < 4; rr++) {
        int rl = rg * 4 + rr;
        int row = row0 + rl;
        if (row >= n) continue;
        float4 res;
        if (MODE == 0) {
            float4 gb = ((const float4*)bias_or_dinv)[cg];
            float4 xv = *(float4*)&Xl[rl][cg * 4];
            res.x = xv.x / (1.f + __expf(-(acc[rr][0] + gb.x)));
            res.y = xv.y / (1.f + __expf(-(acc[rr][1] + gb.y)));
            res.z = xv.z / (1.f + __expf(-(acc[rr][2] + gb.z)));
            res.w = xv.w / (1.f + __expf(-(acc[rr][3] + gb.w)));
        } else {
            float di = bias_or_dinv[row];
            res.x = acc[rr][0] * di;
            res.y = acc[rr][1] * di;
            res.z = acc[rr][2] * di;
            res.w = acc[rr][3] * di;
        }
        *(float4*)&out[(size_t)row * 128 + cg * 4] = res;
    }
}

// ---------------------------------------------------------------------------
// SpMM gather: out[i,:] = relu?( dinv[i]*(g[i,:] + sum_{e in row i} g[col[e],:]) + bias )
// 32 lanes per row (float4 each), 8 rows per 256-thread block.
// ---------------------------------------------------------------------------
__global__ void spmm_kernel(const float4* __restrict__ g4, const int* __restrict__ rowptr,
                            const int* __restrict__ col, const float* __restrict__ dinv,
                            const float* __restrict__ bias, float4* __restrict__ out4,
                            int n, int do_relu) {
    int grp = threadIdx.x >> 5;
    int i = blockIdx.x * 8 + grp;
    if (i >= n) return;
    int c = threadIdx.x & 31;

    float4 acc = g4[(size_t)i * 32 + c];  // self loop term (g already has dinv[src])
    int e0 = rowptr[i], e1 = rowptr[i + 1];
    int e = e0;
    for (; e + 2 <= e1; e += 2) {
        int s0 = col[e], s1 = col[e + 1];
        float4 v0 = g4[(size_t)s0 * 32 + c];
        float4 v1 = g4[(size_t)s1 * 32 + c];
        acc.x += v0.x + v1.x;
        acc.y += v0.y + v1.y;
        acc.z += v0.z + v1.z;
        acc.w += v0.w + v1.w;
    }
    if (e < e1) {
        int s0 = col[e];
        float4 v0 = g4[(size_t)s0 * 32 + c];
        acc.x += v0.x; acc.y += v0.y; acc.z += v0.z; acc.w += v0.w;
    }
    float di = dinv[i];
    float4 bv = ((const float4*)bias)[c];
    float4 r;
    r.x = fmaf(acc.x, di, bv.x);
    r.y = fmaf(acc.y, di, bv.y);
    r.z = fmaf(acc.z, di, bv.z);
    r.w = fmaf(acc.w, di, bv.w);
    if (do_relu) {
        r.x = fmaxf(r.x, 0.f); r.y = fmaxf(r.y, 0.f);
        r.z = fmaxf(r.z, 0.f); r.w = fmaxf(r.w, 0.f);
    }
    out4[(size_t)i * 32 + c] = r;
}

extern "C" void kernel_launch(void* const* d_in, const int* in_sizes, int n_in,
                              void* d_out, int out_size, void* d_ws, size_t ws_size,
                              hipStream_t stream) {
    const float* x      = (const float*)d_in[0];
    const int*   ei     = (const int*)d_in[1];
    const float* gate_W = (const float*)d_in[2];
    const float* gate_b = (const float*)d_in[3];
    const float* W1     = (const float*)d_in[4];
    const float* b1     = (const float*)d_in[5];
    const float* W2     = (const float*)d_in[6];
    const float* b2     = (const float*)d_in[7];
    float* out = (float*)d_out;

    const int N = in_sizes[0] / 128;
    const int E = in_sizes[1] / 2;
    const int* src = ei;
    const int* dst = ei + E;

    // workspace carve-up (~110.5 MB total)
    char* p = (char*)d_ws;
    auto alloc = [&](size_t bytes) { char* q = p; p += (bytes + 255) & ~(size_t)255; return q; };
    int*   deg    = (int*)alloc((size_t)N * 4);
    int*   rowptr = (int*)alloc(((size_t)N + 1) * 4);
    int*   cursor = (int*)alloc((size_t)N * 4);
    float* dinv   = (float*)alloc((size_t)N * 4);
    int*   colb   = (int*)alloc((size_t)E * 4);
    int nc = (N + 1023) / 1024;
    int*   bsum   = (int*)alloc((size_t)nc * 4);
    int*   cbase  = (int*)alloc((size_t)nc * 4);
    float* hbuf   = (float*)alloc((size_t)N * 128 * 4);
    float* gbuf   = (float*)alloc((size_t)N * 128 * 4);

    const int tb = 256;

    // --- CSR build (dst identical for both layers) ---
    hipMemsetAsync(deg, 0, (size_t)N * 4, stream);
    deg_kernel<<<(E + tb - 1) / tb, tb, 0, stream>>>(dst, deg, E);
    dinv_kernel<<<(N + tb - 1) / tb, tb, 0, stream>>>(deg, dinv, N);
    chunk_sum_kernel<<<nc, 256, 0, stream>>>(deg, bsum, N);
    chunk_scan_kernel<<<1, 1024, 0, stream>>>(bsum, cbase, rowptr, nc, N);
    scan_write_kernel<<<nc, 256, 0, stream>>>(deg, cbase, rowptr, cursor, N);
    fill_kernel<<<(E + tb - 1) / tb, tb, 0, stream>>>(src, dst, cursor, colb, E);

    // --- dense + sparse pipeline ---
    int gblocks = (N + 63) / 64;
    gemm_kernel<0><<<gblocks, 512, 0, stream>>>(x, gate_W, gate_b, hbuf, N);      // h = x*sig(x@gW+gb)
    gemm_kernel<1><<<gblocks, 512, 0, stream>>>(hbuf, W1, dinv, gbuf, N);         // g1 = (h@W1)*dinv
    spmm_kernel<<<(N + 7) / 8, 256, 0, stream>>>((const float4*)gbuf, rowptr, colb,
                                                 dinv, b1, (float4*)hbuf, N, 1);  // h1 = relu(...)
    gemm_kernel<1><<<gblocks, 512, 0, stream>>>(hbuf, W2, dinv, gbuf, N);         // g2 = (h1@W2)*dinv
    spmm_kernel<<<(N + 7) / 8, 256, 0, stream>>>((const float4*)gbuf, rowptr, colb,
                                                 dinv, b2, (float4*)out, N, 0);   // out
}

// Round 2
// 495.311 us; speedup vs baseline: 1.3208x; 1.3208x over previous
//
#include <hip/hip_runtime.h>
#include <hip/hip_bf16.h>
#include <math.h>

// ---------------------------------------------------------------------------
// GCNEncoderWithGate: h = x*sigmoid(x@gW+gb); 2x { g=(h@W)*dinv; out[d]=dinv[d]*(sum g[src]+g[d])+b }
// R2: bucketed CSR build (bucket = 256 dst nodes). Eliminates per-edge global
// atomics + partial-line scatter writes that made fill_kernel 137us.
//   partition: LDS hist + per-(block,bucket) reservation + packed 4B edge scatter
//   bucket_fill: LDS-local deg/scan/fill -> rowptr, dinv, col (coalesced writes)
// ---------------------------------------------------------------------------

#define BUCKET_SHIFT 8
#define BUCKET_W 256
#define CAP 4864          // max edges/bucket; E/NB=4092, sigma=64 -> 12 sigma slack
#define NB_MAX 512

// pack: (dstLocal << 17) | src   (src < 2^17, dstLocal < 256)
__global__ void partition_kernel(const int* __restrict__ src, const int* __restrict__ dst,
                                 int* __restrict__ bucketCursor, unsigned int* __restrict__ part,
                                 int E, int NB, int chunk) {
    __shared__ int hist[NB_MAX];
    __shared__ int basec[NB_MAX];
    int t = threadIdx.x;
    int b = blockIdx.x;
    int e0 = b * chunk;
    int e1 = min(E, e0 + chunk);

    for (int i = t; i < NB; i += 256) hist[i] = 0;
    __syncthreads();
    for (int e = e0 + t; e < e1; e += 256) {
        int bb = dst[e] >> BUCKET_SHIFT;
        atomicAdd(&hist[bb], 1);
    }
    __syncthreads();
    for (int i = t; i < NB; i += 256) {
        int c = hist[i];
        basec[i] = c ? atomicAdd(&bucketCursor[i], c) : 0;
    }
    __syncthreads();
    for (int i = t; i < NB; i += 256) hist[i] = 0;
    __syncthreads();
    for (int e = e0 + t; e < e1; e += 256) {
        int d = dst[e], s = src[e];
        int bb = d >> BUCKET_SHIFT;
        int r = atomicAdd(&hist[bb], 1);
        int pos = basec[bb] + r;
        if (pos < CAP)
            part[(size_t)bb * CAP + pos] = ((unsigned int)(d & (BUCKET_W - 1)) << 17) | (unsigned int)s;
    }
}

// exclusive scan of bucket counts -> bucketBase[NB+1]
__global__ void bucket_scan_kernel(const int* __restrict__ bucketCursor,
                                   int* __restrict__ bucketBase, int NB) {
    __shared__ int sm[NB_MAX];
    int t = threadIdx.x;
    int v = (t < NB) ? min(bucketCursor[t], CAP) : 0;
    sm[t] = v;
    __syncthreads();
    for (int off = 1; off < NB_MAX; off <<= 1) {
        int a = (t >= off) ? sm[t - off] : 0;
        __syncthreads();
        sm[t] += a;
        __syncthreads();
    }
    if (t < NB) bucketBase[t + 1] = sm[t];
    if (t == 0) bucketBase[0] = 0;
}

// one block per bucket: LDS deg + scan + placement. Writes rowptr, dinv, col.
__launch_bounds__(256, 2)
__global__ void bucket_fill_kernel(const unsigned int* __restrict__ part,
                                   const int* __restrict__ bucketBase,
                                   int* __restrict__ rowptr, float* __restrict__ dinv,
                                   int* __restrict__ col, int N) {
    __shared__ unsigned int eLDS[CAP];
    __shared__ int deg[BUCKET_W];
    __shared__ int cur[BUCKET_W];
    __shared__ int wsum[4];

    int b = blockIdx.x, t = threadIdx.x;
    int base = bucketBase[b];
    int cnt = bucketBase[b + 1] - base;

    for (int i = t; i < cnt; i += 256) eLDS[i] = part[(size_t)b * CAP + i];
    deg[t] = 0;
    __syncthreads();
    for (int i = t; i < cnt; i += 256) atomicAdd(&deg[eLDS[i] >> 17], 1);
    __syncthreads();

    // 256-wide exclusive scan of deg (4 waves)
    int v = deg[t];
    int incl = v;
    int lane = t & 63, w = t >> 6;
    for (int off = 1; off < 64; off <<= 1) {
        int u = __shfl_up(incl, off, 64);
        if (lane >= off) incl += u;
    }
    if (lane == 63) wsum[w] = incl;
    __syncthreads();
    int add = 0;
#pragma unroll
    for (int j = 0; j < 4; j++) if (j < w) add += wsum[j];
    int excl = add + incl - v;
    cur[t] = excl;

    int gnode = b * BUCKET_W + t;
    if (gnode < N) {
        rowptr[gnode] = base + excl;
        dinv[gnode] = rsqrtf((float)(v + 1));   // +1 self loop
    }
    if (b == gridDim.x - 1 && t == 0) rowptr[N] = base + cnt;
    __syncthreads();

    for (int i = t; i < cnt; i += 256) {
        unsigned int ev = eLDS[i];
        int dl = ev >> 17;
        int p = atomicAdd(&cur[dl], 1);
        col[base + p] = (int)(ev & 0x1FFFFu);
    }
}

// ---------------------------------------------------------------------------
// GEMM: out[row,:] = epilogue(A[row,:] @ W)
// MODE 0: out = A * sigmoid(A@W + bias)          (bias_or_dinv = gate_b[128])
// MODE 1: out = (A@W) * dinv[row]                (bias_or_dinv = dinv[N])
// ---------------------------------------------------------------------------
template <int MODE>
__launch_bounds__(512, 1)
__global__ void gemm_kernel(const float* __restrict__ A, const float* __restrict__ W,
                            const float* __restrict__ bias_or_dinv, float* __restrict__ out,
                            int n) {
    __shared__ float Wl[128][128];
    __shared__ float Xl[64][132];
    int t = threadIdx.x;

    const float4* W4 = (const float4*)W;
    float4* Wl4 = (float4*)&Wl[0][0];
#pragma unroll
    for (int i = t; i < 4096; i += 512) Wl4[i] = W4[i];

    int row0 = blockIdx.x * 64;
    for (int i = t; i < 2048; i += 512) {
        int r = i >> 5, c4 = i & 31;
        int row = row0 + r;
        float4 v = make_float4(0.f, 0.f, 0.f, 0.f);
        if (row < n) v = *(const float4*)&A[(size_t)row * 128 + c4 * 4];
        *(float4*)&Xl[r][c4 * 4] = v;
    }
    __syncthreads();

    int cg = t & 31;
    int rg = t >> 5;
    float acc[4][4];
#pragma unroll
    for (int a = 0; a < 4; a++)
#pragma unroll
        for (int b = 0; b < 4; b++) acc[a][b] = 0.f;

    for (int k = 0; k < 128; k += 4) {
        float4 w0 = *(float4*)&Wl[k + 0][cg * 4];
        float4 w1 = *(float4*)&Wl[k + 1][cg * 4];
        float4 w2 = *(float4*)&Wl[k + 2][cg * 4];
        float4 w3 = *(float4*)&Wl[k + 3][cg * 4];
#pragma unroll
        for (int rr = 0; rr < 4; rr++) {
            float4 xv = *(float4*)&Xl[rg * 4 + rr][k];
            acc[rr][0] = fmaf(xv.x, w0.x, acc[rr][0]);
            acc[rr][1] = fmaf(xv.x, w0.y, acc[rr][1]);
            acc[rr][2] = fmaf(xv.x, w0.z, acc[rr][2]);
            acc[rr][3] = fmaf(xv.x, w0.w, acc[rr][3]);
            acc[rr][0] = fmaf(xv.y, w1.x, acc[rr][0]);
            acc[rr][1] = fmaf(xv.y, w1.y, acc[rr][1]);
            acc[rr][2] = fmaf(xv.y, w1.z, acc[rr][2]);
            acc[rr][3] = fmaf(xv.y, w1.w, acc[rr][3]);
            acc[rr][0] = fmaf(xv.z, w2.x, acc[rr][0]);
            acc[rr][1] = fmaf(xv.z, w2.y, acc[rr][1]);
            acc[rr][2] = fmaf(xv.z, w2.z, acc[rr][2]);
            acc[rr][3] = fmaf(xv.z, w2.w, acc[rr][3]);
            acc[rr][0] = fmaf(xv.w, w3.x, acc[rr][0]);
            acc[rr][1] = fmaf(xv.w, w3.y, acc[rr][1]);
            acc[rr][2] = fmaf(xv.w, w3.z, acc[rr][2]);
            acc[rr][3] = fmaf(xv.w, w3.w, acc[rr][3]);
        }
    }

#pragma unroll
    for (int rr = 0; rr < 4; rr++) {
        int rl = rg * 4 + rr;
        int row = row0 + rl;
        if (row >= n) continue;
        float4 res;
        if (MODE == 0) {
            float4 gb = ((const float4*)bias_or_dinv)[cg];
            float4 xv = *(float4*)&Xl[rl][cg * 4];
            res.x = xv.x / (1.f + __expf(-(acc[rr][0] + gb.x)));
            res.y = xv.y / (1.f + __expf(-(acc[rr][1] + gb.y)));
            res.z = xv.z / (1.f + __expf(-(acc[rr][2] + gb.z)));
            res.w = xv.w / (1.f + __expf(-(acc[rr][3] + gb.w)));
        } else {
            float di = bias_or_dinv[row];
            res.x = acc[rr][0] * di;
            res.y = acc[rr][1] * di;
            res.z = acc[rr][2] * di;
            res.w = acc[rr][3] * di;
        }
        *(float4*)&out[(size_t)row * 128 + cg * 4] = res;
    }
}

// ---------------------------------------------------------------------------
// SpMM gather: out[i,:] = relu?( dinv[i]*(g[i,:] + sum_{e in row i} g[col[e],:]) + bias )
// ---------------------------------------------------------------------------
__global__ void spmm_kernel(const float4* __restrict__ g4, const int* __restrict__ rowptr,
                            const int* __restrict__ col, const float* __restrict__ dinv,
                            const float* __restrict__ bias, float4* __restrict__ out4,
                            int n, int do_relu) {
    int grp = threadIdx.x >> 5;
    int i = blockIdx.x * 8 + grp;
    if (i >= n) return;
    int c = threadIdx.x & 31;

    float4 acc = g4[(size_t)i * 32 + c];
    int e0 = rowptr[i], e1 = rowptr[i + 1];
    int e = e0;
    for (; e + 2 <= e1; e += 2) {
        int s0 = col[e], s1 = col[e + 1];
        float4 v0 = g4[(size_t)s0 * 32 + c];
        float4 v1 = g4[(size_t)s1 * 32 + c];
        acc.x += v0.x + v1.x;
        acc.y += v0.y + v1.y;
        acc.z += v0.z + v1.z;
        acc.w += v0.w + v1.w;
    }
    if (e < e1) {
        int s0 = col[e];
        float4 v0 = g4[(size_t)s0 * 32 + c];
        acc.x += v0.x; acc.y += v0.y; acc.z += v0.z; acc.w += v0.w;
    }
    float di = dinv[i];
    float4 bv = ((const float4*)bias)[c];
    float4 r;
    r.x = fmaf(acc.x, di, bv.x);
    r.y = fmaf(acc.y, di, bv.y);
    r.z = fmaf(acc.z, di, bv.z);
    r.w = fmaf(acc.w, di, bv.w);
    if (do_relu) {
        r.x = fmaxf(r.x, 0.f); r.y = fmaxf(r.y, 0.f);
        r.z = fmaxf(r.z, 0.f); r.w = fmaxf(r.w, 0.f);
    }
    out4[(size_t)i * 32 + c] = r;
}

extern "C" void kernel_launch(void* const* d_in, const int* in_sizes, int n_in,
                              void* d_out, int out_size, void* d_ws, size_t ws_size,
                              hipStream_t stream) {
    const float* x      = (const float*)d_in[0];
    const int*   ei     = (const int*)d_in[1];
    const float* gate_W = (const float*)d_in[2];
    const float* gate_b = (const float*)d_in[3];
    const float* W1     = (const float*)d_in[4];
    const float* b1     = (const float*)d_in[5];
    const float* W2     = (const float*)d_in[6];
    const float* b2     = (const float*)d_in[7];
    float* out = (float*)d_out;

    const int N = in_sizes[0] / 128;
    const int E = in_sizes[1] / 2;
    const int* src = ei;
    const int* dst = ei + E;
    const int NB = (N + BUCKET_W - 1) / BUCKET_W;   // 391 for N=100000

    char* p = (char*)d_ws;
    auto alloc = [&](size_t bytes) { char* q = p; p += (bytes + 255) & ~(size_t)255; return q; };
    int*   rowptr  = (int*)alloc(((size_t)N + 1) * 4);
    float* dinv    = (float*)alloc((size_t)N * 4);
    int*   colb    = (int*)alloc((size_t)E * 4);
    int*   bcursor = (int*)alloc((size_t)NB * 4);
    int*   bbase   = (int*)alloc(((size_t)NB + 1) * 4);
    float* hbuf    = (float*)alloc((size_t)N * 128 * 4);
    float* gbuf    = (float*)alloc((size_t)N * 128 * 4);
    // part[] aliases hbuf: dead before gemm<0> writes hbuf (stream-ordered)
    unsigned int* part = (unsigned int*)hbuf;   // NB*CAP*4 = 7.6 MB << 51.2 MB

    // --- CSR build ---
    hipMemsetAsync(bcursor, 0, (size_t)NB * 4, stream);
    const int pblocks = 256;
    const int chunk = (E + pblocks - 1) / pblocks;
    partition_kernel<<<pblocks, 256, 0, stream>>>(src, dst, bcursor, part, E, NB, chunk);
    bucket_scan_kernel<<<1, NB_MAX, 0, stream>>>(bcursor, bbase, NB);
    bucket_fill_kernel<<<NB, 256, 0, stream>>>(part, bbase, rowptr, dinv, colb, N);

    // --- dense + sparse pipeline ---
    int gblocks = (N + 63) / 64;
    gemm_kernel<0><<<gblocks, 512, 0, stream>>>(x, gate_W, gate_b, hbuf, N);
    gemm_kernel<1><<<gblocks, 512, 0, stream>>>(hbuf, W1, dinv, gbuf, N);
    spmm_kernel<<<(N + 7) / 8, 256, 0, stream>>>((const float4*)gbuf, rowptr, colb,
                                                 dinv, b1, (float4*)hbuf, N, 1);
    gemm_kernel<1><<<gblocks, 512, 0, stream>>>(hbuf, W2, dinv, gbuf, N);
    spmm_kernel<<<(N + 7) / 8, 256, 0, stream>>>((const float4*)gbuf, rowptr, colb,
                                                 dinv, b2, (float4*)out, N, 0);
}

// Round 3
// 388.580 us; speedup vs baseline: 1.6836x; 1.2747x over previous
//
#include <hip/hip_runtime.h>
#include <hip/hip_bf16.h>
#include <math.h>

// ---------------------------------------------------------------------------
// GCNEncoderWithGate: h = x*sigmoid(x@gW+gb); 2x { g=(h@W)*dinv; out[d]=dinv[d]*(sum g[src]+g[d])+b }
// R3: bf16 message matrix g. spmm was gather-traffic-bound (400MB fetch/dispatch,
// 512B/edge). g stored bf16 -> 256B/edge, fp32 accumulation. GEMM epilogue
// (MODE 1) converts to bf16; spmm unpacks via bit ops.
// ---------------------------------------------------------------------------

#define BUCKET_SHIFT 8
#define BUCKET_W 256
#define CAP 4864
#define NB_MAX 512

__device__ __forceinline__ unsigned short f2bf(float x) {
    unsigned int u = __float_as_uint(x);
    unsigned int r = (u + 0x7FFFu + ((u >> 16) & 1u)) >> 16;   // RNE
    return (unsigned short)r;
}
__device__ __forceinline__ float blo(unsigned int u) { return __uint_as_float(u << 16); }
__device__ __forceinline__ float bhi(unsigned int u) { return __uint_as_float(u & 0xFFFF0000u); }

// pack: (dstLocal << 17) | src
__global__ void partition_kernel(const int* __restrict__ src, const int* __restrict__ dst,
                                 int* __restrict__ bucketCursor, unsigned int* __restrict__ part,
                                 int E, int NB, int chunk) {
    __shared__ int hist[NB_MAX];
    __shared__ int basec[NB_MAX];
    int t = threadIdx.x;
    int b = blockIdx.x;
    int e0 = b * chunk;
    int e1 = min(E, e0 + chunk);

    for (int i = t; i < NB; i += 256) hist[i] = 0;
    __syncthreads();
    for (int e = e0 + t; e < e1; e += 256) {
        int bb = dst[e] >> BUCKET_SHIFT;
        atomicAdd(&hist[bb], 1);
    }
    __syncthreads();
    for (int i = t; i < NB; i += 256) {
        int c = hist[i];
        basec[i] = c ? atomicAdd(&bucketCursor[i], c) : 0;
    }
    __syncthreads();
    for (int i = t; i < NB; i += 256) hist[i] = 0;
    __syncthreads();
    for (int e = e0 + t; e < e1; e += 256) {
        int d = dst[e], s = src[e];
        int bb = d >> BUCKET_SHIFT;
        int r = atomicAdd(&hist[bb], 1);
        int pos = basec[bb] + r;
        if (pos < CAP)
            part[(size_t)bb * CAP + pos] = ((unsigned int)(d & (BUCKET_W - 1)) << 17) | (unsigned int)s;
    }
}

__global__ void bucket_scan_kernel(const int* __restrict__ bucketCursor,
                                   int* __restrict__ bucketBase, int NB) {
    __shared__ int sm[NB_MAX];
    int t = threadIdx.x;
    int v = (t < NB) ? min(bucketCursor[t], CAP) : 0;
    sm[t] = v;
    __syncthreads();
    for (int off = 1; off < NB_MAX; off <<= 1) {
        int a = (t >= off) ? sm[t - off] : 0;
        __syncthreads();
        sm[t] += a;
        __syncthreads();
    }
    if (t < NB) bucketBase[t + 1] = sm[t];
    if (t == 0) bucketBase[0] = 0;
}

__launch_bounds__(256, 2)
__global__ void bucket_fill_kernel(const unsigned int* __restrict__ part,
                                   const int* __restrict__ bucketBase,
                                   int* __restrict__ rowptr, float* __restrict__ dinv,
                                   int* __restrict__ col, int N) {
    __shared__ unsigned int eLDS[CAP];
    __shared__ int deg[BUCKET_W];
    __shared__ int cur[BUCKET_W];
    __shared__ int wsum[4];

    int b = blockIdx.x, t = threadIdx.x;
    int base = bucketBase[b];
    int cnt = bucketBase[b + 1] - base;

    for (int i = t; i < cnt; i += 256) eLDS[i] = part[(size_t)b * CAP + i];
    deg[t] = 0;
    __syncthreads();
    for (int i = t; i < cnt; i += 256) atomicAdd(&deg[eLDS[i] >> 17], 1);
    __syncthreads();

    int v = deg[t];
    int incl = v;
    int lane = t & 63, w = t >> 6;
    for (int off = 1; off < 64; off <<= 1) {
        int u = __shfl_up(incl, off, 64);
        if (lane >= off) incl += u;
    }
    if (lane == 63) wsum[w] = incl;
    __syncthreads();
    int add = 0;
#pragma unroll
    for (int j = 0; j < 4; j++) if (j < w) add += wsum[j];
    int excl = add + incl - v;
    cur[t] = excl;

    int gnode = b * BUCKET_W + t;
    if (gnode < N) {
        rowptr[gnode] = base + excl;
        dinv[gnode] = rsqrtf((float)(v + 1));
    }
    if (b == gridDim.x - 1 && t == 0) rowptr[N] = base + cnt;
    __syncthreads();

    for (int i = t; i < cnt; i += 256) {
        unsigned int ev = eLDS[i];
        int dl = ev >> 17;
        int p = atomicAdd(&cur[dl], 1);
        col[base + p] = (int)(ev & 0x1FFFFu);
    }
}

// ---------------------------------------------------------------------------
// GEMM: MODE 0: out(fp32) = A * sigmoid(A@W + gate_b)
//       MODE 1: out(bf16) = (A@W) * dinv[row]
// ---------------------------------------------------------------------------
template <int MODE>
__launch_bounds__(512, 1)
__global__ void gemm_kernel(const float* __restrict__ A, const float* __restrict__ W,
                            const float* __restrict__ bias_or_dinv, void* __restrict__ outv,
                            int n) {
    __shared__ float Wl[128][128];
    __shared__ float Xl[64][132];
    int t = threadIdx.x;

    const float4* W4 = (const float4*)W;
    float4* Wl4 = (float4*)&Wl[0][0];
#pragma unroll
    for (int i = t; i < 4096; i += 512) Wl4[i] = W4[i];

    int row0 = blockIdx.x * 64;
    for (int i = t; i < 2048; i += 512) {
        int r = i >> 5, c4 = i & 31;
        int row = row0 + r;
        float4 v = make_float4(0.f, 0.f, 0.f, 0.f);
        if (row < n) v = *(const float4*)&A[(size_t)row * 128 + c4 * 4];
        *(float4*)&Xl[r][c4 * 4] = v;
    }
    __syncthreads();

    int cg = t & 31;
    int rg = t >> 5;
    float acc[4][4];
#pragma unroll
    for (int a = 0; a < 4; a++)
#pragma unroll
        for (int b = 0; b < 4; b++) acc[a][b] = 0.f;

    for (int k = 0; k < 128; k += 4) {
        float4 w0 = *(float4*)&Wl[k + 0][cg * 4];
        float4 w1 = *(float4*)&Wl[k + 1][cg * 4];
        float4 w2 = *(float4*)&Wl[k + 2][cg * 4];
        float4 w3 = *(float4*)&Wl[k + 3][cg * 4];
#pragma unroll
        for (int rr = 0; rr < 4; rr++) {
            float4 xv = *(float4*)&Xl[rg * 4 + rr][k];
            acc[rr][0] = fmaf(xv.x, w0.x, acc[rr][0]);
            acc[rr][1] = fmaf(xv.x, w0.y, acc[rr][1]);
            acc[rr][2] = fmaf(xv.x, w0.z, acc[rr][2]);
            acc[rr][3] = fmaf(xv.x, w0.w, acc[rr][3]);
            acc[rr][0] = fmaf(xv.y, w1.x, acc[rr][0]);
            acc[rr][1] = fmaf(xv.y, w1.y, acc[rr][1]);
            acc[rr][2] = fmaf(xv.y, w1.z, acc[rr][2]);
            acc[rr][3] = fmaf(xv.y, w1.w, acc[rr][3]);
            acc[rr][0] = fmaf(xv.z, w2.x, acc[rr][0]);
            acc[rr][1] = fmaf(xv.z, w2.y, acc[rr][1]);
            acc[rr][2] = fmaf(xv.z, w2.z, acc[rr][2]);
            acc[rr][3] = fmaf(xv.z, w2.w, acc[rr][3]);
            acc[rr][0] = fmaf(xv.w, w3.x, acc[rr][0]);
            acc[rr][1] = fmaf(xv.w, w3.y, acc[rr][1]);
            acc[rr][2] = fmaf(xv.w, w3.z, acc[rr][2]);
            acc[rr][3] = fmaf(xv.w, w3.w, acc[rr][3]);
        }
    }

#pragma unroll
    for (int rr = 0; rr < 4; rr++) {
        int rl = rg * 4 + rr;
        int row = row0 + rl;
        if (row >= n) continue;
        if (MODE == 0) {
            float4 gb = ((const float4*)bias_or_dinv)[cg];
            float4 xv = *(float4*)&Xl[rl][cg * 4];
            float4 res;
            res.x = xv.x / (1.f + __expf(-(acc[rr][0] + gb.x)));
            res.y = xv.y / (1.f + __expf(-(acc[rr][1] + gb.y)));
            res.z = xv.z / (1.f + __expf(-(acc[rr][2] + gb.z)));
            res.w = xv.w / (1.f + __expf(-(acc[rr][3] + gb.w)));
            *(float4*)&((float*)outv)[(size_t)row * 128 + cg * 4] = res;
        } else {
            float di = bias_or_dinv[row];
            ushort4 q;
            q.x = f2bf(acc[rr][0] * di);
            q.y = f2bf(acc[rr][1] * di);
            q.z = f2bf(acc[rr][2] * di);
            q.w = f2bf(acc[rr][3] * di);
            *(ushort4*)&((unsigned short*)outv)[(size_t)row * 128 + cg * 4] = q;
        }
    }
}

// ---------------------------------------------------------------------------
// SpMM gather (bf16 g): out[i,:] = relu?( dinv[i]*(g[i,:] + sum g[col[e],:]) + bias )
// 16 lanes/row, each lane: uint4 = 8 bf16 features. fp32 accumulation.
// ---------------------------------------------------------------------------
__global__ void spmm_kernel(const uint4* __restrict__ g16, const int* __restrict__ rowptr,
                            const int* __restrict__ col, const float* __restrict__ dinv,
                            const float* __restrict__ bias, float* __restrict__ out,
                            int n, int do_relu) {
    int grp = threadIdx.x >> 4;
    int i = blockIdx.x * 16 + grp;
    if (i >= n) return;
    int c = threadIdx.x & 15;   // features c*8 .. c*8+7

    float acc[8];
    uint4 sv = g16[(size_t)i * 16 + c];   // self-loop term
    acc[0] = blo(sv.x); acc[1] = bhi(sv.x);
    acc[2] = blo(sv.y); acc[3] = bhi(sv.y);
    acc[4] = blo(sv.z); acc[5] = bhi(sv.z);
    acc[6] = blo(sv.w); acc[7] = bhi(sv.w);

    int e0 = rowptr[i], e1 = rowptr[i + 1];
    int e = e0;
    for (; e + 4 <= e1; e += 4) {
        int s0 = col[e], s1 = col[e + 1], s2 = col[e + 2], s3 = col[e + 3];
        uint4 v0 = g16[(size_t)s0 * 16 + c];
        uint4 v1 = g16[(size_t)s1 * 16 + c];
        uint4 v2 = g16[(size_t)s2 * 16 + c];
        uint4 v3 = g16[(size_t)s3 * 16 + c];
        acc[0] += (blo(v0.x) + blo(v1.x)) + (blo(v2.x) + blo(v3.x));
        acc[1] += (bhi(v0.x) + bhi(v1.x)) + (bhi(v2.x) + bhi(v3.x));
        acc[2] += (blo(v0.y) + blo(v1.y)) + (blo(v2.y) + blo(v3.y));
        acc[3] += (bhi(v0.y) + bhi(v1.y)) + (bhi(v2.y) + bhi(v3.y));
        acc[4] += (blo(v0.z) + blo(v1.z)) + (blo(v2.z) + blo(v3.z));
        acc[5] += (bhi(v0.z) + bhi(v1.z)) + (bhi(v2.z) + bhi(v3.z));
        acc[6] += (blo(v0.w) + blo(v1.w)) + (blo(v2.w) + blo(v3.w));
        acc[7] += (bhi(v0.w) + bhi(v1.w)) + (bhi(v2.w) + bhi(v3.w));
    }
    for (; e < e1; e++) {
        int s0 = col[e];
        uint4 v0 = g16[(size_t)s0 * 16 + c];
        acc[0] += blo(v0.x); acc[1] += bhi(v0.x);
        acc[2] += blo(v0.y); acc[3] += bhi(v0.y);
        acc[4] += blo(v0.z); acc[5] += bhi(v0.z);
        acc[6] += blo(v0.w); acc[7] += bhi(v0.w);
    }

    float di = dinv[i];
    const float4* b4 = (const float4*)bias;
    float4 bv0 = b4[c * 2], bv1 = b4[c * 2 + 1];
    float4 r0, r1;
    r0.x = fmaf(acc[0], di, bv0.x);
    r0.y = fmaf(acc[1], di, bv0.y);
    r0.z = fmaf(acc[2], di, bv0.z);
    r0.w = fmaf(acc[3], di, bv0.w);
    r1.x = fmaf(acc[4], di, bv1.x);
    r1.y = fmaf(acc[5], di, bv1.y);
    r1.z = fmaf(acc[6], di, bv1.z);
    r1.w = fmaf(acc[7], di, bv1.w);
    if (do_relu) {
        r0.x = fmaxf(r0.x, 0.f); r0.y = fmaxf(r0.y, 0.f);
        r0.z = fmaxf(r0.z, 0.f); r0.w = fmaxf(r0.w, 0.f);
        r1.x = fmaxf(r1.x, 0.f); r1.y = fmaxf(r1.y, 0.f);
        r1.z = fmaxf(r1.z, 0.f); r1.w = fmaxf(r1.w, 0.f);
    }
    float4* o4 = (float4*)&out[(size_t)i * 128 + c * 8];
    o4[0] = r0;
    o4[1] = r1;
}

extern "C" void kernel_launch(void* const* d_in, const int* in_sizes, int n_in,
                              void* d_out, int out_size, void* d_ws, size_t ws_size,
                              hipStream_t stream) {
    const float* x      = (const float*)d_in[0];
    const int*   ei     = (const int*)d_in[1];
    const float* gate_W = (const float*)d_in[2];
    const float* gate_b = (const float*)d_in[3];
    const float* W1     = (const float*)d_in[4];
    const float* b1     = (const float*)d_in[5];
    const float* W2     = (const float*)d_in[6];
    const float* b2     = (const float*)d_in[7];
    float* out = (float*)d_out;

    const int N = in_sizes[0] / 128;
    const int E = in_sizes[1] / 2;
    const int* src = ei;
    const int* dst = ei + E;
    const int NB = (N + BUCKET_W - 1) / BUCKET_W;

    char* p = (char*)d_ws;
    auto alloc = [&](size_t bytes) { char* q = p; p += (bytes + 255) & ~(size_t)255; return q; };
    int*   rowptr  = (int*)alloc(((size_t)N + 1) * 4);
    float* dinv    = (float*)alloc((size_t)N * 4);
    int*   colb    = (int*)alloc((size_t)E * 4);
    int*   bcursor = (int*)alloc((size_t)NB * 4);
    int*   bbase   = (int*)alloc(((size_t)NB + 1) * 4);
    float* hbuf    = (float*)alloc((size_t)N * 128 * 4);
    unsigned short* gbuf16 = (unsigned short*)alloc((size_t)N * 128 * 2);
    unsigned int* part = (unsigned int*)hbuf;   // aliases hbuf (dead until gemm<0>)

    // --- CSR build ---
    hipMemsetAsync(bcursor, 0, (size_t)NB * 4, stream);
    const int pblocks = 256;
    const int chunk = (E + pblocks - 1) / pblocks;
    partition_kernel<<<pblocks, 256, 0, stream>>>(src, dst, bcursor, part, E, NB, chunk);
    bucket_scan_kernel<<<1, NB_MAX, 0, stream>>>(bcursor, bbase, NB);
    bucket_fill_kernel<<<NB, 256, 0, stream>>>(part, bbase, rowptr, dinv, colb, N);

    // --- dense + sparse pipeline ---
    int gblocks = (N + 63) / 64;
    int sblocks = (N + 15) / 16;
    gemm_kernel<0><<<gblocks, 512, 0, stream>>>(x, gate_W, gate_b, hbuf, N);
    gemm_kernel<1><<<gblocks, 512, 0, stream>>>(hbuf, W1, dinv, gbuf16, N);
    spmm_kernel<<<sblocks, 256, 0, stream>>>((const uint4*)gbuf16, rowptr, colb,
                                             dinv, b1, hbuf, N, 1);
    gemm_kernel<1><<<gblocks, 512, 0, stream>>>(hbuf, W2, dinv, gbuf16, N);
    spmm_kernel<<<sblocks, 256, 0, stream>>>((const uint4*)gbuf16, rowptr, colb,
                                             dinv, b2, out, N, 0);
}

// Round 4
// 296.411 us; speedup vs baseline: 2.2071x; 1.3110x over previous
//
#include <hip/hip_runtime.h>
#include <hip/hip_bf16.h>
#include <math.h>

// ---------------------------------------------------------------------------
// GCNEncoderWithGate R4: GEMMs moved to split-bf16 MFMA (x=x_hi+x_lo, 3-term
// product => fp32-accurate to ~1e-5, matrix pipe instead of 157TF VALU).
// W staged in LDS as hi/lo bf16, XOR-swizzled 16B blocks (2-way bank = free).
// A rows -> registers (converted in-VGPR). CSR build + bf16 spmm unchanged.
// ---------------------------------------------------------------------------

#define BUCKET_SHIFT 8
#define BUCKET_W 256
#define CAP 4864
#define NB_MAX 512

typedef __attribute__((ext_vector_type(8))) short bf16x8;
typedef __attribute__((ext_vector_type(4))) float f32x4;

__device__ __forceinline__ unsigned short f2bf(float x) {
    unsigned int u = __float_as_uint(x);
    unsigned int r = (u + 0x7FFFu + ((u >> 16) & 1u)) >> 16;   // RNE
    return (unsigned short)r;
}
__device__ __forceinline__ float blo(unsigned int u) { return __uint_as_float(u << 16); }
__device__ __forceinline__ float bhi(unsigned int u) { return __uint_as_float(u & 0xFFFF0000u); }

// split 8 fp32 -> hi/lo bf16x8
__device__ __forceinline__ void cvt_hilo8(const float* v, bf16x8& hi, bf16x8& lo) {
#pragma unroll
    for (int j = 0; j < 8; j++) {
        unsigned short h = f2bf(v[j]);
        float hf = __uint_as_float((unsigned int)h << 16);
        hi[j] = (short)h;
        lo[j] = (short)f2bf(v[j] - hf);
    }
}

// ------------------------------ CSR build ----------------------------------
__global__ void partition_kernel(const int* __restrict__ src, const int* __restrict__ dst,
                                 int* __restrict__ bucketCursor, unsigned int* __restrict__ part,
                                 int E, int NB, int chunk) {
    __shared__ int hist[NB_MAX];
    __shared__ int basec[NB_MAX];
    int t = threadIdx.x;
    int b = blockIdx.x;
    int e0 = b * chunk;
    int e1 = min(E, e0 + chunk);

    for (int i = t; i < NB; i += 256) hist[i] = 0;
    __syncthreads();
    for (int e = e0 + t; e < e1; e += 256) {
        int bb = dst[e] >> BUCKET_SHIFT;
        atomicAdd(&hist[bb], 1);
    }
    __syncthreads();
    for (int i = t; i < NB; i += 256) {
        int c = hist[i];
        basec[i] = c ? atomicAdd(&bucketCursor[i], c) : 0;
    }
    __syncthreads();
    for (int i = t; i < NB; i += 256) hist[i] = 0;
    __syncthreads();
    for (int e = e0 + t; e < e1; e += 256) {
        int d = dst[e], s = src[e];
        int bb = d >> BUCKET_SHIFT;
        int r = atomicAdd(&hist[bb], 1);
        int pos = basec[bb] + r;
        if (pos < CAP)
            part[(size_t)bb * CAP + pos] = ((unsigned int)(d & (BUCKET_W - 1)) << 17) | (unsigned int)s;
    }
}

__global__ void bucket_scan_kernel(const int* __restrict__ bucketCursor,
                                   int* __restrict__ bucketBase, int NB) {
    __shared__ int sm[NB_MAX];
    int t = threadIdx.x;
    int v = (t < NB) ? min(bucketCursor[t], CAP) : 0;
    sm[t] = v;
    __syncthreads();
    for (int off = 1; off < NB_MAX; off <<= 1) {
        int a = (t >= off) ? sm[t - off] : 0;
        __syncthreads();
        sm[t] += a;
        __syncthreads();
    }
    if (t < NB) bucketBase[t + 1] = sm[t];
    if (t == 0) bucketBase[0] = 0;
}

__launch_bounds__(256, 2)
__global__ void bucket_fill_kernel(const unsigned int* __restrict__ part,
                                   const int* __restrict__ bucketBase,
                                   int* __restrict__ rowptr, float* __restrict__ dinv,
                                   int* __restrict__ col, int N) {
    __shared__ unsigned int eLDS[CAP];
    __shared__ int deg[BUCKET_W];
    __shared__ int cur[BUCKET_W];
    __shared__ int wsum[4];

    int b = blockIdx.x, t = threadIdx.x;
    int base = bucketBase[b];
    int cnt = bucketBase[b + 1] - base;

    for (int i = t; i < cnt; i += 256) eLDS[i] = part[(size_t)b * CAP + i];
    deg[t] = 0;
    __syncthreads();
    for (int i = t; i < cnt; i += 256) atomicAdd(&deg[eLDS[i] >> 17], 1);
    __syncthreads();

    int v = deg[t];
    int incl = v;
    int lane = t & 63, w = t >> 6;
    for (int off = 1; off < 64; off <<= 1) {
        int u = __shfl_up(incl, off, 64);
        if (lane >= off) incl += u;
    }
    if (lane == 63) wsum[w] = incl;
    __syncthreads();
    int add = 0;
#pragma unroll
    for (int j = 0; j < 4; j++) if (j < w) add += wsum[j];
    int excl = add + incl - v;
    cur[t] = excl;

    int gnode = b * BUCKET_W + t;
    if (gnode < N) {
        rowptr[gnode] = base + excl;
        dinv[gnode] = rsqrtf((float)(v + 1));
    }
    if (b == gridDim.x - 1 && t == 0) rowptr[N] = base + cnt;
    __syncthreads();

    for (int i = t; i < cnt; i += 256) {
        unsigned int ev = eLDS[i];
        int dl = ev >> 17;
        int p = atomicAdd(&cur[dl], 1);
        col[base + p] = (int)(ev & 0x1FFFFu);
    }
}

// ------------------------------ MFMA GEMM ----------------------------------
// out[m,:] = epilogue(A[m,:] @ W), M rows, K=N=128. Split-bf16, 3-term.
// Block 256 thr = 4 waves; BM=128 (wave owns 32 rows = 2 row-tiles of 16).
// LDS: W as hi/lo bf16x8 blocks, swizzled widx = col*16 + (kb ^ (col&15)).
// MODE 0: out fp32 = A * sigmoid(A@W + gate_b)
// MODE 1: out bf16 = (A@W) * dinv[row]
template <int MODE>
__launch_bounds__(256)
__global__ void gemm_mfma_kernel(const float* __restrict__ A, const float* __restrict__ W,
                                 const float* __restrict__ bias_or_dinv, void* __restrict__ outv,
                                 int n) {
    __shared__ uint4 WtHi[2048];   // [col][kb swizzled] 32 KB
    __shared__ uint4 WtLo[2048];   // 32 KB

    int t = threadIdx.x;

    // --- stage W hi/lo into LDS (coalesced 512B rows per j) ---
#pragma unroll
    for (int it = 0; it < 8; it++) {
        int idx = it * 256 + t;
        int c = idx & 127;        // col
        int kb = idx >> 7;        // 16B k-block (8 bf16)
        float v[8];
#pragma unroll
        for (int j = 0; j < 8; j++) v[j] = W[(size_t)(kb * 8 + j) * 128 + c];
        bf16x8 hi, lo;
        cvt_hilo8(v, hi, lo);
        int widx = c * 16 + (kb ^ (c & 15));
        WtHi[widx] = *(uint4*)&hi;
        WtLo[widx] = *(uint4*)&lo;
    }

    // --- load A rows -> registers, split hi/lo ---
    int lane = t & 63, wv = t >> 6;
    int rowBase = blockIdx.x * 128 + wv * 32;      // wave owns 32 rows
    bf16x8 Ahi[2][4], Alo[2][4];
#pragma unroll
    for (int rt = 0; rt < 2; rt++) {
        int row = rowBase + rt * 16 + (lane & 15);
        int rc = min(row, n - 1);
        const float* ap = A + (size_t)rc * 128 + (lane >> 4) * 8;
#pragma unroll
        for (int s = 0; s < 4; s++) {
            float v[8];
            *(float4*)&v[0] = *(const float4*)&ap[s * 32];
            *(float4*)&v[4] = *(const float4*)&ap[s * 32 + 4];
            cvt_hilo8(v, Ahi[rt][s], Alo[rt][s]);
        }
    }
    __syncthreads();

    // --- MFMA main: acc[rt][nt] over 4 k-steps, 3-term split ---
    f32x4 acc[2][8];
#pragma unroll
    for (int rt = 0; rt < 2; rt++)
#pragma unroll
        for (int nt = 0; nt < 8; nt++) acc[rt][nt] = (f32x4)(0.f);

#pragma unroll
    for (int s = 0; s < 4; s++) {
        int kb = s * 4 + (lane >> 4);
#pragma unroll
        for (int nt = 0; nt < 8; nt++) {
            int c = nt * 16 + (lane & 15);
            int widx = c * 16 + (kb ^ (lane & 15));
            bf16x8 bh = *(bf16x8*)&WtHi[widx];
            bf16x8 bl = *(bf16x8*)&WtLo[widx];
#pragma unroll
            for (int rt = 0; rt < 2; rt++) {
                acc[rt][nt] = __builtin_amdgcn_mfma_f32_16x16x32_bf16(Ahi[rt][s], bh, acc[rt][nt], 0, 0, 0);
                acc[rt][nt] = __builtin_amdgcn_mfma_f32_16x16x32_bf16(Alo[rt][s], bh, acc[rt][nt], 0, 0, 0);
                acc[rt][nt] = __builtin_amdgcn_mfma_f32_16x16x32_bf16(Ahi[rt][s], bl, acc[rt][nt], 0, 0, 0);
            }
        }
    }

    // --- epilogue. C/D: col = lane&15, row = (lane>>4)*4 + reg ---
#pragma unroll
    for (int rt = 0; rt < 2; rt++) {
        int rbase = rowBase + rt * 16 + (lane >> 4) * 4;
        if (MODE == 1) {
            float di[4];
#pragma unroll
            for (int r = 0; r < 4; r++) di[r] = bias_or_dinv[min(rbase + r, n - 1)];
#pragma unroll
            for (int nt = 0; nt < 8; nt++) {
                int c = nt * 16 + (lane & 15);
#pragma unroll
                for (int r = 0; r < 4; r++) {
                    int row = rbase + r;
                    if (row < n)
                        ((unsigned short*)outv)[(size_t)row * 128 + c] = f2bf(acc[rt][nt][r] * di[r]);
                }
            }
        } else {
#pragma unroll
            for (int nt = 0; nt < 8; nt++) {
                int c = nt * 16 + (lane & 15);
                float gb = bias_or_dinv[c];
#pragma unroll
                for (int r = 0; r < 4; r++) {
                    int row = rbase + r;
                    if (row < n) {
                        float xv = A[(size_t)row * 128 + c];
                        ((float*)outv)[(size_t)row * 128 + c] =
                            xv / (1.f + __expf(-(acc[rt][nt][r] + gb)));
                    }
                }
            }
        }
    }
}

// ------------------------------ SpMM (bf16 g) ------------------------------
__global__ void spmm_kernel(const uint4* __restrict__ g16, const int* __restrict__ rowptr,
                            const int* __restrict__ col, const float* __restrict__ dinv,
                            const float* __restrict__ bias, float* __restrict__ out,
                            int n, int do_relu) {
    int grp = threadIdx.x >> 4;
    int i = blockIdx.x * 16 + grp;
    if (i >= n) return;
    int c = threadIdx.x & 15;

    float acc[8];
    uint4 sv = g16[(size_t)i * 16 + c];
    acc[0] = blo(sv.x); acc[1] = bhi(sv.x);
    acc[2] = blo(sv.y); acc[3] = bhi(sv.y);
    acc[4] = blo(sv.z); acc[5] = bhi(sv.z);
    acc[6] = blo(sv.w); acc[7] = bhi(sv.w);

    int e0 = rowptr[i], e1 = rowptr[i + 1];
    int e = e0;
    for (; e + 4 <= e1; e += 4) {
        int s0 = col[e], s1 = col[e + 1], s2 = col[e + 2], s3 = col[e + 3];
        uint4 v0 = g16[(size_t)s0 * 16 + c];
        uint4 v1 = g16[(size_t)s1 * 16 + c];
        uint4 v2 = g16[(size_t)s2 * 16 + c];
        uint4 v3 = g16[(size_t)s3 * 16 + c];
        acc[0] += (blo(v0.x) + blo(v1.x)) + (blo(v2.x) + blo(v3.x));
        acc[1] += (bhi(v0.x) + bhi(v1.x)) + (bhi(v2.x) + bhi(v3.x));
        acc[2] += (blo(v0.y) + blo(v1.y)) + (blo(v2.y) + blo(v3.y));
        acc[3] += (bhi(v0.y) + bhi(v1.y)) + (bhi(v2.y) + bhi(v3.y));
        acc[4] += (blo(v0.z) + blo(v1.z)) + (blo(v2.z) + blo(v3.z));
        acc[5] += (bhi(v0.z) + bhi(v1.z)) + (bhi(v2.z) + bhi(v3.z));
        acc[6] += (blo(v0.w) + blo(v1.w)) + (blo(v2.w) + blo(v3.w));
        acc[7] += (bhi(v0.w) + bhi(v1.w)) + (bhi(v2.w) + bhi(v3.w));
    }
    for (; e < e1; e++) {
        int s0 = col[e];
        uint4 v0 = g16[(size_t)s0 * 16 + c];
        acc[0] += blo(v0.x); acc[1] += bhi(v0.x);
        acc[2] += blo(v0.y); acc[3] += bhi(v0.y);
        acc[4] += blo(v0.z); acc[5] += bhi(v0.z);
        acc[6] += blo(v0.w); acc[7] += bhi(v0.w);
    }

    float di = dinv[i];
    const float4* b4 = (const float4*)bias;
    float4 bv0 = b4[c * 2], bv1 = b4[c * 2 + 1];
    float4 r0, r1;
    r0.x = fmaf(acc[0], di, bv0.x);
    r0.y = fmaf(acc[1], di, bv0.y);
    r0.z = fmaf(acc[2], di, bv0.z);
    r0.w = fmaf(acc[3], di, bv0.w);
    r1.x = fmaf(acc[4], di, bv1.x);
    r1.y = fmaf(acc[5], di, bv1.y);
    r1.z = fmaf(acc[6], di, bv1.z);
    r1.w = fmaf(acc[7], di, bv1.w);
    if (do_relu) {
        r0.x = fmaxf(r0.x, 0.f); r0.y = fmaxf(r0.y, 0.f);
        r0.z = fmaxf(r0.z, 0.f); r0.w = fmaxf(r0.w, 0.f);
        r1.x = fmaxf(r1.x, 0.f); r1.y = fmaxf(r1.y, 0.f);
        r1.z = fmaxf(r1.z, 0.f); r1.w = fmaxf(r1.w, 0.f);
    }
    float4* o4 = (float4*)&out[(size_t)i * 128 + c * 8];
    o4[0] = r0;
    o4[1] = r1;
}

extern "C" void kernel_launch(void* const* d_in, const int* in_sizes, int n_in,
                              void* d_out, int out_size, void* d_ws, size_t ws_size,
                              hipStream_t stream) {
    const float* x      = (const float*)d_in[0];
    const int*   ei     = (const int*)d_in[1];
    const float* gate_W = (const float*)d_in[2];
    const float* gate_b = (const float*)d_in[3];
    const float* W1     = (const float*)d_in[4];
    const float* b1     = (const float*)d_in[5];
    const float* W2     = (const float*)d_in[6];
    const float* b2     = (const float*)d_in[7];
    float* out = (float*)d_out;

    const int N = in_sizes[0] / 128;
    const int E = in_sizes[1] / 2;
    const int* src = ei;
    const int* dst = ei + E;
    const int NB = (N + BUCKET_W - 1) / BUCKET_W;

    char* p = (char*)d_ws;
    auto alloc = [&](size_t bytes) { char* q = p; p += (bytes + 255) & ~(size_t)255; return q; };
    int*   rowptr  = (int*)alloc(((size_t)N + 1) * 4);
    float* dinv    = (float*)alloc((size_t)N * 4);
    int*   colb    = (int*)alloc((size_t)E * 4);
    int*   bcursor = (int*)alloc((size_t)NB * 4);
    int*   bbase   = (int*)alloc(((size_t)NB + 1) * 4);
    float* hbuf    = (float*)alloc((size_t)N * 128 * 4);
    unsigned short* gbuf16 = (unsigned short*)alloc((size_t)N * 128 * 2);
    unsigned int* part = (unsigned int*)hbuf;   // aliases hbuf (dead until gemm<0>)

    // --- CSR build ---
    hipMemsetAsync(bcursor, 0, (size_t)NB * 4, stream);
    const int pblocks = 256;
    const int chunk = (E + pblocks - 1) / pblocks;
    partition_kernel<<<pblocks, 256, 0, stream>>>(src, dst, bcursor, part, E, NB, chunk);
    bucket_scan_kernel<<<1, NB_MAX, 0, stream>>>(bcursor, bbase, NB);
    bucket_fill_kernel<<<NB, 256, 0, stream>>>(part, bbase, rowptr, dinv, colb, N);

    // --- dense + sparse pipeline ---
    int gblocks = (N + 127) / 128;
    int sblocks = (N + 15) / 16;
    gemm_mfma_kernel<0><<<gblocks, 256, 0, stream>>>(x, gate_W, gate_b, hbuf, N);
    gemm_mfma_kernel<1><<<gblocks, 256, 0, stream>>>(hbuf, W1, dinv, gbuf16, N);
    spmm_kernel<<<sblocks, 256, 0, stream>>>((const uint4*)gbuf16, rowptr, colb,
                                             dinv, b1, hbuf, N, 1);
    gemm_mfma_kernel<1><<<gblocks, 256, 0, stream>>>(hbuf, W2, dinv, gbuf16, N);
    spmm_kernel<<<sblocks, 256, 0, stream>>>((const uint4*)gbuf16, rowptr, colb,
                                             dinv, b2, out, N, 0);
}

// Round 5
// 264.441 us; speedup vs baseline: 2.4740x; 1.1209x over previous
//
#include <hip/hip_runtime.h>
#include <hip/hip_bf16.h>
#include <math.h>

// ---------------------------------------------------------------------------
// GCNEncoderWithGate R5:
//  - fused gate+W1 kernel: x ->(MFMA z=x@gW)-> LDS z ->(sigmoid,h)-> LDS h(bf16 hi/lo)
//    ->(MFMA g1=h@W1)-> LDS-staged coalesced bf16 stores. h never hits HBM.
//  - W matrices bf16-hi only (A split hi/lo, 2 MFMA/tile): W LDS halved.
//  - all epilogues via LDS staging -> uint4 stores (R4 had 64 scalar stores/thread,
//    2x write amplification).
// CSR build + bf16 spmm unchanged.
// ---------------------------------------------------------------------------

#define BUCKET_SHIFT 8
#define BUCKET_W 256
#define CAP 4864
#define NB_MAX 512
#define ZSTRIDE 132
#define OSTRIDE 136

typedef __attribute__((ext_vector_type(8))) short bf16x8;
typedef __attribute__((ext_vector_type(4))) float f32x4;

__device__ __forceinline__ unsigned short f2bf(float x) {
    unsigned int u = __float_as_uint(x);
    unsigned int r = (u + 0x7FFFu + ((u >> 16) & 1u)) >> 16;   // RNE
    return (unsigned short)r;
}
__device__ __forceinline__ float blo(unsigned int u) { return __uint_as_float(u << 16); }
__device__ __forceinline__ float bhi(unsigned int u) { return __uint_as_float(u & 0xFFFF0000u); }

__device__ __forceinline__ void cvt_hilo8(const float* v, bf16x8& hi, bf16x8& lo) {
#pragma unroll
    for (int j = 0; j < 8; j++) {
        unsigned short h = f2bf(v[j]);
        float hf = __uint_as_float((unsigned int)h << 16);
        hi[j] = (short)h;
        lo[j] = (short)f2bf(v[j] - hf);
    }
}

__device__ __forceinline__ f32x4 MF(bf16x8 a, bf16x8 b, f32x4 c) {
    return __builtin_amdgcn_mfma_f32_16x16x32_bf16(a, b, c, 0, 0, 0);
}

// z LDS storage: word idx, 4-block XOR swizzle so both the acc-scatter writes
// and the per-row float4 readback stay <=2-way on banks.
__device__ __forceinline__ int zw(int row, int c) {
    return row * ZSTRIDE + (c ^ (4 * ((c >> 5) & 3)));
}

// ------------------------------ CSR build ----------------------------------
__global__ void partition_kernel(const int* __restrict__ src, const int* __restrict__ dst,
                                 int* __restrict__ bucketCursor, unsigned int* __restrict__ part,
                                 int E, int NB, int chunk) {
    __shared__ int hist[NB_MAX];
    __shared__ int basec[NB_MAX];
    int t = threadIdx.x;
    int b = blockIdx.x;
    int e0 = b * chunk;
    int e1 = min(E, e0 + chunk);

    for (int i = t; i < NB; i += 256) hist[i] = 0;
    __syncthreads();
    for (int e = e0 + t; e < e1; e += 256) {
        int bb = dst[e] >> BUCKET_SHIFT;
        atomicAdd(&hist[bb], 1);
    }
    __syncthreads();
    for (int i = t; i < NB; i += 256) {
        int c = hist[i];
        basec[i] = c ? atomicAdd(&bucketCursor[i], c) : 0;
    }
    __syncthreads();
    for (int i = t; i < NB; i += 256) hist[i] = 0;
    __syncthreads();
    for (int e = e0 + t; e < e1; e += 256) {
        int d = dst[e], s = src[e];
        int bb = d >> BUCKET_SHIFT;
        int r = atomicAdd(&hist[bb], 1);
        int pos = basec[bb] + r;
        if (pos < CAP)
            part[(size_t)bb * CAP + pos] = ((unsigned int)(d & (BUCKET_W - 1)) << 17) | (unsigned int)s;
    }
}

__global__ void bucket_scan_kernel(const int* __restrict__ bucketCursor,
                                   int* __restrict__ bucketBase, int NB) {
    __shared__ int sm[NB_MAX];
    int t = threadIdx.x;
    int v = (t < NB) ? min(bucketCursor[t], CAP) : 0;
    sm[t] = v;
    __syncthreads();
    for (int off = 1; off < NB_MAX; off <<= 1) {
        int a = (t >= off) ? sm[t - off] : 0;
        __syncthreads();
        sm[t] += a;
        __syncthreads();
    }
    if (t < NB) bucketBase[t + 1] = sm[t];
    if (t == 0) bucketBase[0] = 0;
}

__launch_bounds__(256, 2)
__global__ void bucket_fill_kernel(const unsigned int* __restrict__ part,
                                   const int* __restrict__ bucketBase,
                                   int* __restrict__ rowptr, float* __restrict__ dinv,
                                   int* __restrict__ col, int N) {
    __shared__ unsigned int eLDS[CAP];
    __shared__ int deg[BUCKET_W];
    __shared__ int cur[BUCKET_W];
    __shared__ int wsum[4];

    int b = blockIdx.x, t = threadIdx.x;
    int base = bucketBase[b];
    int cnt = bucketBase[b + 1] - base;

    for (int i = t; i < cnt; i += 256) eLDS[i] = part[(size_t)b * CAP + i];
    deg[t] = 0;
    __syncthreads();
    for (int i = t; i < cnt; i += 256) atomicAdd(&deg[eLDS[i] >> 17], 1);
    __syncthreads();

    int v = deg[t];
    int incl = v;
    int lane = t & 63, w = t >> 6;
    for (int off = 1; off < 64; off <<= 1) {
        int u = __shfl_up(incl, off, 64);
        if (lane >= off) incl += u;
    }
    if (lane == 63) wsum[w] = incl;
    __syncthreads();
    int add = 0;
#pragma unroll
    for (int j = 0; j < 4; j++) if (j < w) add += wsum[j];
    int excl = add + incl - v;
    cur[t] = excl;

    int gnode = b * BUCKET_W + t;
    if (gnode < N) {
        rowptr[gnode] = base + excl;
        dinv[gnode] = rsqrtf((float)(v + 1));
    }
    if (b == gridDim.x - 1 && t == 0) rowptr[N] = base + cnt;
    __syncthreads();

    for (int i = t; i < cnt; i += 256) {
        unsigned int ev = eLDS[i];
        int dl = ev >> 17;
        int p = atomicAdd(&cur[dl], 1);
        col[base + p] = (int)(ev & 0x1FFFFu);
    }
}

// ------------------------- fused gate + W1 GEMM ----------------------------
// g1(bf16) = ( (x * sigmoid(x@gW + gb)) @ W1 ) * dinv[row]
// 512 thr = 8 waves, BM=128 rows/block, wave owns 16 rows.
// LDS: Wg 32K | W1l 32K | union{ z fp32[128][132] , Hhi+Hlo 64K } = 130 KB.
// OutS (bf16 [128][136]) aliases Wg/W1l after last MFMA.
__global__ __launch_bounds__(512)
void fused_gate_w1_kernel(const float* __restrict__ x, const float* __restrict__ gateW,
                          const float* __restrict__ gate_b, const float* __restrict__ W1,
                          const float* __restrict__ dinv, unsigned short* __restrict__ g1,
                          int n) {
    __shared__ __align__(16) char smem[133120];
    uint4* Wg   = (uint4*)smem;                       // 2048 entries
    uint4* W1l  = (uint4*)(smem + 32768);             // 2048 entries
    float* zbuf = (float*)(smem + 65536);             // 128*132 fp32
    uint4* Hhi  = (uint4*)(smem + 65536);             // aliases zbuf
    uint4* Hlo  = (uint4*)(smem + 65536 + 32768);
    unsigned short* OutS = (unsigned short*)smem;     // [128][OSTRIDE], aliases Wg/W1l

    int t = threadIdx.x;
    int lane = t & 63, wv = t >> 6;
    int blockRow = blockIdx.x * 128;

    // stage W-hi (bf16) for gateW and W1: entry (c, kb) = W[kb*8..kb*8+7][c]
    for (int idx = t; idx < 2048; idx += 512) {
        int c = idx & 127, kb = idx >> 7;
        bf16x8 hg, h1;
#pragma unroll
        for (int j = 0; j < 8; j++) {
            hg[j] = (short)f2bf(gateW[(size_t)(kb * 8 + j) * 128 + c]);
            h1[j] = (short)f2bf(W1[(size_t)(kb * 8 + j) * 128 + c]);
        }
        int widx = c * 16 + (kb ^ (c & 15));
        Wg[widx] = *(uint4*)&hg;
        W1l[widx] = *(uint4*)&h1;
    }

    // A-frags of x (hi/lo split), wave rows = blockRow + wv*16 + (lane&15)
    bf16x8 Ahi[4], Alo[4];
    {
        int arow = blockRow + wv * 16 + (lane & 15);
        const float* ap = x + (size_t)min(arow, n - 1) * 128 + (lane >> 4) * 8;
#pragma unroll
        for (int s = 0; s < 4; s++) {
            float v[8];
            *(float4*)&v[0] = *(const float4*)&ap[s * 32];
            *(float4*)&v[4] = *(const float4*)&ap[s * 32 + 4];
            cvt_hilo8(v, Ahi[s], Alo[s]);
        }
    }
    __syncthreads();

    // MFMA-1: z = x @ gateW (A hi+lo vs W-hi)
    f32x4 acc[8];
#pragma unroll
    for (int nt = 0; nt < 8; nt++) acc[nt] = (f32x4)(0.f);
#pragma unroll
    for (int s = 0; s < 4; s++) {
        int kb = s * 4 + (lane >> 4);
#pragma unroll
        for (int nt = 0; nt < 8; nt++) {
            int c = nt * 16 + (lane & 15);
            bf16x8 bh = *(bf16x8*)&Wg[c * 16 + (kb ^ (lane & 15))];
            acc[nt] = MF(Ahi[s], bh, acc[nt]);
            acc[nt] = MF(Alo[s], bh, acc[nt]);
        }
    }

    // scatter z to LDS (C/D layout: col=lane&15, row=(lane>>4)*4+r)
    int rl0 = wv * 16 + (lane >> 4) * 4;
#pragma unroll
    for (int nt = 0; nt < 8; nt++) {
        int c = nt * 16 + (lane & 15);
#pragma unroll
        for (int r = 0; r < 4; r++) zbuf[zw(rl0 + r, c)] = acc[nt][r];
    }
    __syncthreads();

    // phase 3: h = x * sigmoid(z + gb); pack to Hhi/Hlo (same LDS region as z)
    {
        int row = t >> 2;
        int c0 = (t & 3) * 32;
        int grow = min(blockRow + row, n - 1);
        float hv[32];
#pragma unroll
        for (int j = 0; j < 8; j++) {
            int c = c0 + j * 4;
            float4 zv = *(float4*)&zbuf[zw(row, c)];
            float4 xv = *(const float4*)&x[(size_t)grow * 128 + c];
            float4 gb = *(const float4*)&gate_b[c];
            hv[j * 4 + 0] = xv.x / (1.f + __expf(-(zv.x + gb.x)));
            hv[j * 4 + 1] = xv.y / (1.f + __expf(-(zv.y + gb.y)));
            hv[j * 4 + 2] = xv.z / (1.f + __expf(-(zv.z + gb.z)));
            hv[j * 4 + 3] = xv.w / (1.f + __expf(-(zv.w + gb.w)));
        }
        __syncthreads();   // all z reads complete before H overwrites the region
#pragma unroll
        for (int kbi = 0; kbi < 4; kbi++) {
            int kb = (c0 >> 3) + kbi;
            bf16x8 hi, lo;
            cvt_hilo8(&hv[kbi * 8], hi, lo);
            int widx = row * 16 + (kb ^ (row & 15));
            Hhi[widx] = *(uint4*)&hi;
            Hlo[widx] = *(uint4*)&lo;
        }
    }
    __syncthreads();

    // load H A-frags and run MFMA-2: g1 = h @ W1
    bf16x8 Hh[4], Hl[4];
    {
        int hrow = wv * 16 + (lane & 15);
#pragma unroll
        for (int s = 0; s < 4; s++) {
            int kb = s * 4 + (lane >> 4);
            int widx = hrow * 16 + (kb ^ (hrow & 15));
            Hh[s] = *(bf16x8*)&Hhi[widx];
            Hl[s] = *(bf16x8*)&Hlo[widx];
        }
    }
    f32x4 acc2[8];
#pragma unroll
    for (int nt = 0; nt < 8; nt++) acc2[nt] = (f32x4)(0.f);
#pragma unroll
    for (int s = 0; s < 4; s++) {
        int kb = s * 4 + (lane >> 4);
#pragma unroll
        for (int nt = 0; nt < 8; nt++) {
            int c = nt * 16 + (lane & 15);
            bf16x8 bh = *(bf16x8*)&W1l[c * 16 + (kb ^ (lane & 15))];
            acc2[nt] = MF(Hh[s], bh, acc2[nt]);
            acc2[nt] = MF(Hl[s], bh, acc2[nt]);
        }
    }

    // epilogue: *dinv, ->bf16, LDS-stage, coalesced uint4 stores
    float di[4];
#pragma unroll
    for (int r = 0; r < 4; r++) di[r] = dinv[min(blockRow + rl0 + r, n - 1)];
    __syncthreads();   // all Wg/W1l reads done before OutS aliases them
#pragma unroll
    for (int nt = 0; nt < 8; nt++) {
        int c = nt * 16 + (lane & 15);
#pragma unroll
        for (int r = 0; r < 4; r++)
            OutS[(rl0 + r) * OSTRIDE + c] = f2bf(acc2[nt][r] * di[r]);
    }
    __syncthreads();
    {
        int row = t >> 2;
        int c0 = (t & 3) * 32;
        int grow = blockRow + row;
        if (grow < n) {
#pragma unroll
            for (int j = 0; j < 4; j++) {
                uint4 v = *(uint4*)&OutS[row * OSTRIDE + c0 + j * 8];
                *(uint4*)&g1[(size_t)grow * 128 + c0 + j * 8] = v;
            }
        }
    }
}

// ------------------------------ W2 GEMM ------------------------------------
// g2(bf16) = (h1 @ W2) * dinv[row]; same structure, single GEMM.
__global__ __launch_bounds__(512)
void gemm_w2_kernel(const float* __restrict__ h1, const float* __restrict__ W2,
                    const float* __restrict__ dinv, unsigned short* __restrict__ g2,
                    int n) {
    __shared__ __align__(16) char smem[67584];
    uint4* Wl = (uint4*)smem;                              // 32 KB
    unsigned short* OutS = (unsigned short*)(smem + 32768); // [128][OSTRIDE]

    int t = threadIdx.x;
    int lane = t & 63, wv = t >> 6;
    int blockRow = blockIdx.x * 128;

    for (int idx = t; idx < 2048; idx += 512) {
        int c = idx & 127, kb = idx >> 7;
        bf16x8 hb;
#pragma unroll
        for (int j = 0; j < 8; j++) hb[j] = (short)f2bf(W2[(size_t)(kb * 8 + j) * 128 + c]);
        Wl[c * 16 + (kb ^ (c & 15))] = *(uint4*)&hb;
    }

    bf16x8 Ah[4], Al[4];
    {
        int arow = blockRow + wv * 16 + (lane & 15);
        const float* ap = h1 + (size_t)min(arow, n - 1) * 128 + (lane >> 4) * 8;
#pragma unroll
        for (int s = 0; s < 4; s++) {
            float v[8];
            *(float4*)&v[0] = *(const float4*)&ap[s * 32];
            *(float4*)&v[4] = *(const float4*)&ap[s * 32 + 4];
            cvt_hilo8(v, Ah[s], Al[s]);
        }
    }
    __syncthreads();

    f32x4 acc[8];
#pragma unroll
    for (int nt = 0; nt < 8; nt++) acc[nt] = (f32x4)(0.f);
#pragma unroll
    for (int s = 0; s < 4; s++) {
        int kb = s * 4 + (lane >> 4);
#pragma unroll
        for (int nt = 0; nt < 8; nt++) {
            int c = nt * 16 + (lane & 15);
            bf16x8 bh = *(bf16x8*)&Wl[c * 16 + (kb ^ (lane & 15))];
            acc[nt] = MF(Ah[s], bh, acc[nt]);
            acc[nt] = MF(Al[s], bh, acc[nt]);
        }
    }

    int rl0 = wv * 16 + (lane >> 4) * 4;
    float di[4];
#pragma unroll
    for (int r = 0; r < 4; r++) di[r] = dinv[min(blockRow + rl0 + r, n - 1)];
#pragma unroll
    for (int nt = 0; nt < 8; nt++) {
        int c = nt * 16 + (lane & 15);
#pragma unroll
        for (int r = 0; r < 4; r++)
            OutS[(rl0 + r) * OSTRIDE + c] = f2bf(acc[nt][r] * di[r]);
    }
    __syncthreads();
    {
        int row = t >> 2;
        int c0 = (t & 3) * 32;
        int grow = blockRow + row;
        if (grow < n) {
#pragma unroll
            for (int j = 0; j < 4; j++) {
                uint4 v = *(uint4*)&OutS[row * OSTRIDE + c0 + j * 8];
                *(uint4*)&g2[(size_t)grow * 128 + c0 + j * 8] = v;
            }
        }
    }
}

// ------------------------------ SpMM (bf16 g) ------------------------------
__global__ void spmm_kernel(const uint4* __restrict__ g16, const int* __restrict__ rowptr,
                            const int* __restrict__ col, const float* __restrict__ dinv,
                            const float* __restrict__ bias, float* __restrict__ out,
                            int n, int do_relu) {
    int grp = threadIdx.x >> 4;
    int i = blockIdx.x * 16 + grp;
    if (i >= n) return;
    int c = threadIdx.x & 15;

    float acc[8];
    uint4 sv = g16[(size_t)i * 16 + c];
    acc[0] = blo(sv.x); acc[1] = bhi(sv.x);
    acc[2] = blo(sv.y); acc[3] = bhi(sv.y);
    acc[4] = blo(sv.z); acc[5] = bhi(sv.z);
    acc[6] = blo(sv.w); acc[7] = bhi(sv.w);

    int e0 = rowptr[i], e1 = rowptr[i + 1];
    int e = e0;
    for (; e + 4 <= e1; e += 4) {
        int s0 = col[e], s1 = col[e + 1], s2 = col[e + 2], s3 = col[e + 3];
        uint4 v0 = g16[(size_t)s0 * 16 + c];
        uint4 v1 = g16[(size_t)s1 * 16 + c];
        uint4 v2 = g16[(size_t)s2 * 16 + c];
        uint4 v3 = g16[(size_t)s3 * 16 + c];
        acc[0] += (blo(v0.x) + blo(v1.x)) + (blo(v2.x) + blo(v3.x));
        acc[1] += (bhi(v0.x) + bhi(v1.x)) + (bhi(v2.x) + bhi(v3.x));
        acc[2] += (blo(v0.y) + blo(v1.y)) + (blo(v2.y) + blo(v3.y));
        acc[3] += (bhi(v0.y) + bhi(v1.y)) + (bhi(v2.y) + bhi(v3.y));
        acc[4] += (blo(v0.z) + blo(v1.z)) + (blo(v2.z) + blo(v3.z));
        acc[5] += (bhi(v0.z) + bhi(v1.z)) + (bhi(v2.z) + bhi(v3.z));
        acc[6] += (blo(v0.w) + blo(v1.w)) + (blo(v2.w) + blo(v3.w));
        acc[7] += (bhi(v0.w) + bhi(v1.w)) + (bhi(v2.w) + bhi(v3.w));
    }
    for (; e < e1; e++) {
        int s0 = col[e];
        uint4 v0 = g16[(size_t)s0 * 16 + c];
        acc[0] += blo(v0.x); acc[1] += bhi(v0.x);
        acc[2] += blo(v0.y); acc[3] += bhi(v0.y);
        acc[4] += blo(v0.z); acc[5] += bhi(v0.z);
        acc[6] += blo(v0.w); acc[7] += bhi(v0.w);
    }

    float di = dinv[i];
    const float4* b4 = (const float4*)bias;
    float4 bv0 = b4[c * 2], bv1 = b4[c * 2 + 1];
    float4 r0, r1;
    r0.x = fmaf(acc[0], di, bv0.x);
    r0.y = fmaf(acc[1], di, bv0.y);
    r0.z = fmaf(acc[2], di, bv0.z);
    r0.w = fmaf(acc[3], di, bv0.w);
    r1.x = fmaf(acc[4], di, bv1.x);
    r1.y = fmaf(acc[5], di, bv1.y);
    r1.z = fmaf(acc[6], di, bv1.z);
    r1.w = fmaf(acc[7], di, bv1.w);
    if (do_relu) {
        r0.x = fmaxf(r0.x, 0.f); r0.y = fmaxf(r0.y, 0.f);
        r0.z = fmaxf(r0.z, 0.f); r0.w = fmaxf(r0.w, 0.f);
        r1.x = fmaxf(r1.x, 0.f); r1.y = fmaxf(r1.y, 0.f);
        r1.z = fmaxf(r1.z, 0.f); r1.w = fmaxf(r1.w, 0.f);
    }
    float4* o4 = (float4*)&out[(size_t)i * 128 + c * 8];
    o4[0] = r0;
    o4[1] = r1;
}

extern "C" void kernel_launch(void* const* d_in, const int* in_sizes, int n_in,
                              void* d_out, int out_size, void* d_ws, size_t ws_size,
                              hipStream_t stream) {
    const float* x      = (const float*)d_in[0];
    const int*   ei     = (const int*)d_in[1];
    const float* gate_W = (const float*)d_in[2];
    const float* gate_b = (const float*)d_in[3];
    const float* W1     = (const float*)d_in[4];
    const float* b1     = (const float*)d_in[5];
    const float* W2     = (const float*)d_in[6];
    const float* b2     = (const float*)d_in[7];
    float* out = (float*)d_out;

    const int N = in_sizes[0] / 128;
    const int E = in_sizes[1] / 2;
    const int* src = ei;
    const int* dst = ei + E;
    const int NB = (N + BUCKET_W - 1) / BUCKET_W;

    char* p = (char*)d_ws;
    auto alloc = [&](size_t bytes) { char* q = p; p += (bytes + 255) & ~(size_t)255; return q; };
    int*   rowptr  = (int*)alloc(((size_t)N + 1) * 4);
    float* dinv    = (float*)alloc((size_t)N * 4);
    int*   colb    = (int*)alloc((size_t)E * 4);
    int*   bcursor = (int*)alloc((size_t)NB * 4);
    int*   bbase   = (int*)alloc(((size_t)NB + 1) * 4);
    float* hbuf    = (float*)alloc((size_t)N * 128 * 4);
    unsigned short* gbuf16 = (unsigned short*)alloc((size_t)N * 128 * 2);
    unsigned int* part = (unsigned int*)hbuf;   // aliases hbuf (dead until spmm-1 writes it)

    // --- CSR build ---
    hipMemsetAsync(bcursor, 0, (size_t)NB * 4, stream);
    const int pblocks = 256;
    const int chunk = (E + pblocks - 1) / pblocks;
    partition_kernel<<<pblocks, 256, 0, stream>>>(src, dst, bcursor, part, E, NB, chunk);
    bucket_scan_kernel<<<1, NB_MAX, 0, stream>>>(bcursor, bbase, NB);
    bucket_fill_kernel<<<NB, 256, 0, stream>>>(part, bbase, rowptr, dinv, colb, N);

    // --- dense + sparse pipeline ---
    int gblocks = (N + 127) / 128;
    int sblocks = (N + 15) / 16;
    fused_gate_w1_kernel<<<gblocks, 512, 0, stream>>>(x, gate_W, gate_b, W1, dinv, gbuf16, N);
    spmm_kernel<<<sblocks, 256, 0, stream>>>((const uint4*)gbuf16, rowptr, colb,
                                             dinv, b1, hbuf, N, 1);
    gemm_w2_kernel<<<gblocks, 512, 0, stream>>>(hbuf, W2, dinv, gbuf16, N);
    spmm_kernel<<<sblocks, 256, 0, stream>>>((const uint4*)gbuf16, rowptr, colb,
                                             dinv, b2, out, N, 0);
}

// Round 6
// 245.562 us; speedup vs baseline: 2.6642x; 1.0769x over previous
//
#include <hip/hip_runtime.h>
#include <hip/hip_bf16.h>
#include <math.h>

// ---------------------------------------------------------------------------
// GCNEncoderWithGate R6: un-fused, all-bf16 dense pipeline.
//  prep: W -> bf16 LDS-image in ws (blocks stage via coalesced uint4 copy)
//  gate: h(bf16) = x * sigmoid(x@gW+gb)   (A hi/lo 2-term MFMA)
//  gemm: g(bf16)  = (A_bf16 @ W) * dinv   (1-term MFMA, shared by W1/W2)
//  spmm: bf16 gather + fp32 accum; layer-1 emits bf16 h1, layer-2 fp32 out.
// R5's 133KB-LDS fused kernel ran at 1 block/CU (2 waves/SIMD) -> 80us;
// these kernels are 67.6KB -> 2 blocks/CU.
// ---------------------------------------------------------------------------

#define BUCKET_SHIFT 8
#define BUCKET_W 256
#define CAP 4864
#define NB_MAX 512
#define OSTRIDE 136   // bf16 elems; 272B/row: 16B-aligned rows, +4 bank rotate per row

typedef __attribute__((ext_vector_type(8))) short bf16x8;
typedef __attribute__((ext_vector_type(4))) float f32x4;

__device__ __forceinline__ unsigned short f2bf(float x) {
    unsigned int u = __float_as_uint(x);
    unsigned int r = (u + 0x7FFFu + ((u >> 16) & 1u)) >> 16;   // RNE
    return (unsigned short)r;
}
__device__ __forceinline__ float blo(unsigned int u) { return __uint_as_float(u << 16); }
__device__ __forceinline__ float bhi(unsigned int u) { return __uint_as_float(u & 0xFFFF0000u); }

__device__ __forceinline__ void cvt_hilo8(const float* v, bf16x8& hi, bf16x8& lo) {
#pragma unroll
    for (int j = 0; j < 8; j++) {
        unsigned short h = f2bf(v[j]);
        float hf = __uint_as_float((unsigned int)h << 16);
        hi[j] = (short)h;
        lo[j] = (short)f2bf(v[j] - hf);
    }
}

__device__ __forceinline__ f32x4 MF(bf16x8 a, bf16x8 b, f32x4 c) {
    return __builtin_amdgcn_mfma_f32_16x16x32_bf16(a, b, c, 0, 0, 0);
}

// ------------------------------ CSR build ----------------------------------
__global__ void partition_kernel(const int* __restrict__ src, const int* __restrict__ dst,
                                 int* __restrict__ bucketCursor, unsigned int* __restrict__ part,
                                 int E, int NB, int chunk) {
    __shared__ int hist[NB_MAX];
    __shared__ int basec[NB_MAX];
    int t = threadIdx.x;
    int b = blockIdx.x;
    int e0 = b * chunk;
    int e1 = min(E, e0 + chunk);

    for (int i = t; i < NB; i += 256) hist[i] = 0;
    __syncthreads();
    for (int e = e0 + t; e < e1; e += 256) {
        int bb = dst[e] >> BUCKET_SHIFT;
        atomicAdd(&hist[bb], 1);
    }
    __syncthreads();
    for (int i = t; i < NB; i += 256) {
        int c = hist[i];
        basec[i] = c ? atomicAdd(&bucketCursor[i], c) : 0;
    }
    __syncthreads();
    for (int i = t; i < NB; i += 256) hist[i] = 0;
    __syncthreads();
    for (int e = e0 + t; e < e1; e += 256) {
        int d = dst[e], s = src[e];
        int bb = d >> BUCKET_SHIFT;
        int r = atomicAdd(&hist[bb], 1);
        int pos = basec[bb] + r;
        if (pos < CAP)
            part[(size_t)bb * CAP + pos] = ((unsigned int)(d & (BUCKET_W - 1)) << 17) | (unsigned int)s;
    }
}

__global__ void bucket_scan_kernel(const int* __restrict__ bucketCursor,
                                   int* __restrict__ bucketBase, int NB) {
    __shared__ int sm[NB_MAX];
    int t = threadIdx.x;
    int v = (t < NB) ? min(bucketCursor[t], CAP) : 0;
    sm[t] = v;
    __syncthreads();
    for (int off = 1; off < NB_MAX; off <<= 1) {
        int a = (t >= off) ? sm[t - off] : 0;
        __syncthreads();
        sm[t] += a;
        __syncthreads();
    }
    if (t < NB) bucketBase[t + 1] = sm[t];
    if (t == 0) bucketBase[0] = 0;
}

__launch_bounds__(256, 2)
__global__ void bucket_fill_kernel(const unsigned int* __restrict__ part,
                                   const int* __restrict__ bucketBase,
                                   int* __restrict__ rowptr, float* __restrict__ dinv,
                                   int* __restrict__ col, int N) {
    __shared__ unsigned int eLDS[CAP];
    __shared__ int deg[BUCKET_W];
    __shared__ int cur[BUCKET_W];
    __shared__ int wsum[4];

    int b = blockIdx.x, t = threadIdx.x;
    int base = bucketBase[b];
    int cnt = bucketBase[b + 1] - base;

    for (int i = t; i < cnt; i += 256) eLDS[i] = part[(size_t)b * CAP + i];
    deg[t] = 0;
    __syncthreads();
    for (int i = t; i < cnt; i += 256) atomicAdd(&deg[eLDS[i] >> 17], 1);
    __syncthreads();

    int v = deg[t];
    int incl = v;
    int lane = t & 63, w = t >> 6;
    for (int off = 1; off < 64; off <<= 1) {
        int u = __shfl_up(incl, off, 64);
        if (lane >= off) incl += u;
    }
    if (lane == 63) wsum[w] = incl;
    __syncthreads();
    int add = 0;
#pragma unroll
    for (int j = 0; j < 4; j++) if (j < w) add += wsum[j];
    int excl = add + incl - v;
    cur[t] = excl;

    int gnode = b * BUCKET_W + t;
    if (gnode < N) {
        rowptr[gnode] = base + excl;
        dinv[gnode] = rsqrtf((float)(v + 1));
    }
    if (b == gridDim.x - 1 && t == 0) rowptr[N] = base + cnt;
    __syncthreads();

    for (int i = t; i < cnt; i += 256) {
        unsigned int ev = eLDS[i];
        int dl = ev >> 17;
        int p = atomicAdd(&cur[dl], 1);
        col[base + p] = (int)(ev & 0x1FFFFu);
    }
}

// --------------------------- weight prep -----------------------------------
// img[w][c*16 + (kb ^ (c&15))] = bf16x8 of W[kb*8+j][c], j=0..7
__global__ void prep_weights_kernel(const float* __restrict__ W0, const float* __restrict__ W1,
                                    const float* __restrict__ W2, uint4* __restrict__ img) {
    int idx = blockIdx.x * 256 + threadIdx.x;   // 3*2048
    int c = idx & 127, kb = (idx >> 7) & 15, w = idx >> 11;
    const float* W = (w == 0) ? W0 : (w == 1) ? W1 : W2;
    bf16x8 hb;
#pragma unroll
    for (int j = 0; j < 8; j++) hb[j] = (short)f2bf(W[(size_t)(kb * 8 + j) * 128 + c]);
    img[w * 2048 + c * 16 + (kb ^ (c & 15))] = *(uint4*)&hb;
}

// ------------------------------ gate GEMM ----------------------------------
// h(bf16) = x * sigmoid(x@gW + gb). 512 thr, BM=128, A hi/lo 2-term.
__global__ __launch_bounds__(512)
void gate_kernel(const float* __restrict__ x, const uint4* __restrict__ gimg,
                 const float* __restrict__ gate_b, unsigned short* __restrict__ hpack,
                 int n) {
    __shared__ uint4 Wl[2048];                       // 32 KB
    __shared__ unsigned short OutS[128 * OSTRIDE];   // 34.8 KB

    int t = threadIdx.x;
    int lane = t & 63, wv = t >> 6;
    int blockRow = blockIdx.x * 128;

    for (int idx = t; idx < 2048; idx += 512) Wl[idx] = gimg[idx];

    bf16x8 Ahi[4], Alo[4];
    {
        int arow = blockRow + wv * 16 + (lane & 15);
        const float* ap = x + (size_t)min(arow, n - 1) * 128 + (lane >> 4) * 8;
#pragma unroll
        for (int s = 0; s < 4; s++) {
            float v[8];
            *(float4*)&v[0] = *(const float4*)&ap[s * 32];
            *(float4*)&v[4] = *(const float4*)&ap[s * 32 + 4];
            cvt_hilo8(v, Ahi[s], Alo[s]);
        }
    }
    __syncthreads();

    f32x4 acc[8];
#pragma unroll
    for (int nt = 0; nt < 8; nt++) acc[nt] = (f32x4)(0.f);
#pragma unroll
    for (int s = 0; s < 4; s++) {
        int kb = s * 4 + (lane >> 4);
#pragma unroll
        for (int nt = 0; nt < 8; nt++) {
            int c = nt * 16 + (lane & 15);
            bf16x8 bh = *(bf16x8*)&Wl[c * 16 + (kb ^ (lane & 15))];
            acc[nt] = MF(Ahi[s], bh, acc[nt]);
            acc[nt] = MF(Alo[s], bh, acc[nt]);
        }
    }

    // epilogue: h = x*sigmoid(z+gb) -> bf16 -> OutS -> coalesced flush
    int rl0 = wv * 16 + (lane >> 4) * 4;
#pragma unroll
    for (int nt = 0; nt < 8; nt++) {
        int c = nt * 16 + (lane & 15);
        float gb = gate_b[c];
#pragma unroll
        for (int r = 0; r < 4; r++) {
            int grow = min(blockRow + rl0 + r, n - 1);
            float xv = x[(size_t)grow * 128 + c];
            float hv = xv / (1.f + __expf(-(acc[nt][r] + gb)));
            OutS[(rl0 + r) * OSTRIDE + c] = f2bf(hv);
        }
    }
    __syncthreads();
    {
        int row = t >> 2;
        int c0 = (t & 3) * 32;
        int grow = blockRow + row;
        if (grow < n) {
#pragma unroll
            for (int j = 0; j < 4; j++) {
                uint4 v = *(uint4*)&OutS[row * OSTRIDE + c0 + j * 8];
                *(uint4*)&hpack[(size_t)grow * 128 + c0 + j * 8] = v;
            }
        }
    }
}

// ------------------------- bf16 GEMM (W1 / W2) -----------------------------
// g(bf16) = (A_bf16 @ W) * dinv[row]. 1-term MFMA.
__global__ __launch_bounds__(512)
void gemm_bf16_kernel(const unsigned short* __restrict__ A, const uint4* __restrict__ wimg,
                      const float* __restrict__ dinv, unsigned short* __restrict__ g,
                      int n) {
    __shared__ uint4 Wl[2048];
    __shared__ unsigned short OutS[128 * OSTRIDE];

    int t = threadIdx.x;
    int lane = t & 63, wv = t >> 6;
    int blockRow = blockIdx.x * 128;

    for (int idx = t; idx < 2048; idx += 512) Wl[idx] = wimg[idx];

    bf16x8 Af[4];
    {
        int arow = blockRow + wv * 16 + (lane & 15);
        const uint4* ap = (const uint4*)(A + (size_t)min(arow, n - 1) * 128);
#pragma unroll
        for (int s = 0; s < 4; s++) {
            uint4 u = ap[(lane >> 4) + s * 4];
            Af[s] = *(bf16x8*)&u;
        }
    }
    __syncthreads();

    f32x4 acc[8];
#pragma unroll
    for (int nt = 0; nt < 8; nt++) acc[nt] = (f32x4)(0.f);
#pragma unroll
    for (int s = 0; s < 4; s++) {
        int kb = s * 4 + (lane >> 4);
#pragma unroll
        for (int nt = 0; nt < 8; nt++) {
            int c = nt * 16 + (lane & 15);
            bf16x8 bh = *(bf16x8*)&Wl[c * 16 + (kb ^ (lane & 15))];
            acc[nt] = MF(Af[s], bh, acc[nt]);
        }
    }

    int rl0 = wv * 16 + (lane >> 4) * 4;
    float di[4];
#pragma unroll
    for (int r = 0; r < 4; r++) di[r] = dinv[min(blockRow + rl0 + r, n - 1)];
#pragma unroll
    for (int nt = 0; nt < 8; nt++) {
        int c = nt * 16 + (lane & 15);
#pragma unroll
        for (int r = 0; r < 4; r++)
            OutS[(rl0 + r) * OSTRIDE + c] = f2bf(acc[nt][r] * di[r]);
    }
    __syncthreads();
    {
        int row = t >> 2;
        int c0 = (t & 3) * 32;
        int grow = blockRow + row;
        if (grow < n) {
#pragma unroll
            for (int j = 0; j < 4; j++) {
                uint4 v = *(uint4*)&OutS[row * OSTRIDE + c0 + j * 8];
                *(uint4*)&g[(size_t)grow * 128 + c0 + j * 8] = v;
            }
        }
    }
}

// ------------------------------ SpMM (bf16 g) ------------------------------
// RELU/PACK: layer1 = <1,1> (bf16 out), layer2 = <0,0> (fp32 out)
template <int RELU, int PACK>
__global__ void spmm_kernel(const uint4* __restrict__ g16, const int* __restrict__ rowptr,
                            const int* __restrict__ col, const float* __restrict__ dinv,
                            const float* __restrict__ bias, void* __restrict__ outv,
                            int n) {
    int grp = threadIdx.x >> 4;
    int i = blockIdx.x * 16 + grp;
    if (i >= n) return;
    int c = threadIdx.x & 15;

    float acc[8];
    uint4 sv = g16[(size_t)i * 16 + c];
    acc[0] = blo(sv.x); acc[1] = bhi(sv.x);
    acc[2] = blo(sv.y); acc[3] = bhi(sv.y);
    acc[4] = blo(sv.z); acc[5] = bhi(sv.z);
    acc[6] = blo(sv.w); acc[7] = bhi(sv.w);

    int e0 = rowptr[i], e1 = rowptr[i + 1];
    int e = e0;
    for (; e + 4 <= e1; e += 4) {
        int s0 = col[e], s1 = col[e + 1], s2 = col[e + 2], s3 = col[e + 3];
        uint4 v0 = g16[(size_t)s0 * 16 + c];
        uint4 v1 = g16[(size_t)s1 * 16 + c];
        uint4 v2 = g16[(size_t)s2 * 16 + c];
        uint4 v3 = g16[(size_t)s3 * 16 + c];
        acc[0] += (blo(v0.x) + blo(v1.x)) + (blo(v2.x) + blo(v3.x));
        acc[1] += (bhi(v0.x) + bhi(v1.x)) + (bhi(v2.x) + bhi(v3.x));
        acc[2] += (blo(v0.y) + blo(v1.y)) + (blo(v2.y) + blo(v3.y));
        acc[3] += (bhi(v0.y) + bhi(v1.y)) + (bhi(v2.y) + bhi(v3.y));
        acc[4] += (blo(v0.z) + blo(v1.z)) + (blo(v2.z) + blo(v3.z));
        acc[5] += (bhi(v0.z) + bhi(v1.z)) + (bhi(v2.z) + bhi(v3.z));
        acc[6] += (blo(v0.w) + blo(v1.w)) + (blo(v2.w) + blo(v3.w));
        acc[7] += (bhi(v0.w) + bhi(v1.w)) + (bhi(v2.w) + bhi(v3.w));
    }
    for (; e < e1; e++) {
        int s0 = col[e];
        uint4 v0 = g16[(size_t)s0 * 16 + c];
        acc[0] += blo(v0.x); acc[1] += bhi(v0.x);
        acc[2] += blo(v0.y); acc[3] += bhi(v0.y);
        acc[4] += blo(v0.z); acc[5] += bhi(v0.z);
        acc[6] += blo(v0.w); acc[7] += bhi(v0.w);
    }

    float di = dinv[i];
    const float4* b4 = (const float4*)bias;
    float4 bv0 = b4[c * 2], bv1 = b4[c * 2 + 1];
    float r0[8];
    r0[0] = fmaf(acc[0], di, bv0.x);
    r0[1] = fmaf(acc[1], di, bv0.y);
    r0[2] = fmaf(acc[2], di, bv0.z);
    r0[3] = fmaf(acc[3], di, bv0.w);
    r0[4] = fmaf(acc[4], di, bv1.x);
    r0[5] = fmaf(acc[5], di, bv1.y);
    r0[6] = fmaf(acc[6], di, bv1.z);
    r0[7] = fmaf(acc[7], di, bv1.w);
    if (RELU) {
#pragma unroll
        for (int j = 0; j < 8; j++) r0[j] = fmaxf(r0[j], 0.f);
    }
    if (PACK) {
        ushort4 q0, q1;
        q0.x = f2bf(r0[0]); q0.y = f2bf(r0[1]); q0.z = f2bf(r0[2]); q0.w = f2bf(r0[3]);
        q1.x = f2bf(r0[4]); q1.y = f2bf(r0[5]); q1.z = f2bf(r0[6]); q1.w = f2bf(r0[7]);
        unsigned short* o = (unsigned short*)outv + (size_t)i * 128 + c * 8;
        *(ushort4*)&o[0] = q0;
        *(ushort4*)&o[4] = q1;
    } else {
        float* o = (float*)outv + (size_t)i * 128 + c * 8;
        *(float4*)&o[0] = *(float4*)&r0[0];
        *(float4*)&o[4] = *(float4*)&r0[4];
    }
}

extern "C" void kernel_launch(void* const* d_in, const int* in_sizes, int n_in,
                              void* d_out, int out_size, void* d_ws, size_t ws_size,
                              hipStream_t stream) {
    const float* x      = (const float*)d_in[0];
    const int*   ei     = (const int*)d_in[1];
    const float* gate_W = (const float*)d_in[2];
    const float* gate_b = (const float*)d_in[3];
    const float* W1     = (const float*)d_in[4];
    const float* b1     = (const float*)d_in[5];
    const float* W2     = (const float*)d_in[6];
    const float* b2     = (const float*)d_in[7];
    float* out = (float*)d_out;

    const int N = in_sizes[0] / 128;
    const int E = in_sizes[1] / 2;
    const int* src = ei;
    const int* dst = ei + E;
    const int NB = (N + BUCKET_W - 1) / BUCKET_W;

    char* p = (char*)d_ws;
    auto alloc = [&](size_t bytes) { char* q = p; p += (bytes + 255) & ~(size_t)255; return q; };
    int*   rowptr  = (int*)alloc(((size_t)N + 1) * 4);
    float* dinv    = (float*)alloc((size_t)N * 4);
    int*   colb    = (int*)alloc((size_t)E * 4);
    int*   bcursor = (int*)alloc((size_t)NB * 4);
    int*   bbase   = (int*)alloc(((size_t)NB + 1) * 4);
    uint4* wimg    = (uint4*)alloc((size_t)3 * 2048 * 16);
    unsigned int*   part    = (unsigned int*)alloc((size_t)NB * CAP * 4);
    unsigned short* hpack   = (unsigned short*)alloc((size_t)N * 128 * 2);
    unsigned short* g16     = (unsigned short*)alloc((size_t)N * 128 * 2);
    unsigned short* h1pack  = (unsigned short*)alloc((size_t)N * 128 * 2);

    // --- weight prep + CSR build ---
    prep_weights_kernel<<<24, 256, 0, stream>>>(gate_W, W1, W2, wimg);
    hipMemsetAsync(bcursor, 0, (size_t)NB * 4, stream);
    const int pblocks = 256;
    const int chunk = (E + pblocks - 1) / pblocks;
    partition_kernel<<<pblocks, 256, 0, stream>>>(src, dst, bcursor, part, E, NB, chunk);
    bucket_scan_kernel<<<1, NB_MAX, 0, stream>>>(bcursor, bbase, NB);
    bucket_fill_kernel<<<NB, 256, 0, stream>>>(part, bbase, rowptr, dinv, colb, N);

    // --- dense + sparse pipeline ---
    int gblocks = (N + 127) / 128;
    int sblocks = (N + 15) / 16;
    gate_kernel<<<gblocks, 512, 0, stream>>>(x, wimg, gate_b, hpack, N);
    gemm_bf16_kernel<<<gblocks, 512, 0, stream>>>(hpack, wimg + 2048, dinv, g16, N);
    spmm_kernel<1, 1><<<sblocks, 256, 0, stream>>>((const uint4*)g16, rowptr, colb,
                                                   dinv, b1, h1pack, N);
    gemm_bf16_kernel<<<gblocks, 512, 0, stream>>>(h1pack, wimg + 4096, dinv, g16, N);
    spmm_kernel<0, 0><<<sblocks, 256, 0, stream>>>((const uint4*)g16, rowptr, colb,
                                                   dinv, b2, out, N);
}

// Round 9
// 215.632 us; speedup vs baseline: 3.0340x; 1.1388x over previous
//
#include <hip/hip_runtime.h>
#include <hip/hip_bf16.h>
#include <math.h>

// ---------------------------------------------------------------------------
// GCNEncoderWithGate R9 (= R8 with the fg race fixed):
//  - fg_kernel race removed: gemm1 (in fg) stores UNSCALED G1 (SCALE=0, never
//    reads dinv); spmm1 applies dinv[src] per edge (DVSRC=1). spmm2 unchanged.
//  - spmm: temporal feature-split halves + nontemporal final store.
//  - dispatches: [prep+init] [partition∪gate] [scan] [fill∪gemm1] [spmm1]
//    [gemm2] [spmm2]
// ---------------------------------------------------------------------------

#define BUCKET_SHIFT 8
#define BUCKET_W 256
#define CAP 4864
#define NB_MAX 512
#define OSTRIDE 136

typedef __attribute__((ext_vector_type(8))) short bf16x8;
typedef __attribute__((ext_vector_type(4))) float f32x4;

__device__ __forceinline__ unsigned short f2bf(float x) {
    unsigned int u = __float_as_uint(x);
    unsigned int r = (u + 0x7FFFu + ((u >> 16) & 1u)) >> 16;   // RNE
    return (unsigned short)r;
}
__device__ __forceinline__ float blo(unsigned int u) { return __uint_as_float(u << 16); }
__device__ __forceinline__ float bhi(unsigned int u) { return __uint_as_float(u & 0xFFFF0000u); }

__device__ __forceinline__ void cvt_hilo8(const float* v, bf16x8& hi, bf16x8& lo) {
#pragma unroll
    for (int j = 0; j < 8; j++) {
        unsigned short h = f2bf(v[j]);
        float hf = __uint_as_float((unsigned int)h << 16);
        hi[j] = (short)h;
        lo[j] = (short)f2bf(v[j] - hf);
    }
}

__device__ __forceinline__ f32x4 MF(bf16x8 a, bf16x8 b, f32x4 c) {
    return __builtin_amdgcn_mfma_f32_16x16x32_bf16(a, b, c, 0, 0, 0);
}

// ---------------------- prep weights + cursor init (1 dispatch) -------------
__global__ __launch_bounds__(512)
void prepinit_kernel(const float* __restrict__ W0, const float* __restrict__ W1,
                     const float* __restrict__ W2, uint4* __restrict__ img,
                     int* __restrict__ bcursor, int NB) {
    int b = blockIdx.x, t = threadIdx.x;
    if (b < 12) {
        int idx = b * 512 + t;            // 0..6143 = 3*2048
        int c = idx & 127, kb = (idx >> 7) & 15, w = idx >> 11;
        const float* W = (w == 0) ? W0 : (w == 1) ? W1 : W2;
        bf16x8 hb;
#pragma unroll
        for (int j = 0; j < 8; j++) hb[j] = (short)f2bf(W[(size_t)(kb * 8 + j) * 128 + c]);
        img[w * 2048 + c * 16 + (kb ^ (c & 15))] = *(uint4*)&hb;
    } else {
        if (t < NB) bcursor[t] = 0;
    }
}

// ---------------------- partition ∪ gate (1 dispatch) -----------------------
__device__ __forceinline__ void partition_body(char* smem, int b, int t,
                                               const int* __restrict__ src,
                                               const int* __restrict__ dst,
                                               int* __restrict__ bucketCursor,
                                               unsigned int* __restrict__ part,
                                               int E, int NB, int chunk) {
    int* hist  = (int*)smem;
    int* basec = hist + NB_MAX;
    int e0 = b * chunk;
    int e1 = min(E, e0 + chunk);

    for (int i = t; i < NB; i += 512) hist[i] = 0;
    __syncthreads();
    for (int e = e0 + t; e < e1; e += 512) {
        int bb = dst[e] >> BUCKET_SHIFT;
        atomicAdd(&hist[bb], 1);
    }
    __syncthreads();
    for (int i = t; i < NB; i += 512) {
        int c = hist[i];
        basec[i] = c ? atomicAdd(&bucketCursor[i], c) : 0;
    }
    __syncthreads();
    for (int i = t; i < NB; i += 512) hist[i] = 0;
    __syncthreads();
    for (int e = e0 + t; e < e1; e += 512) {
        int d = dst[e], s = src[e];
        int bb = d >> BUCKET_SHIFT;
        int r = atomicAdd(&hist[bb], 1);
        int pos = basec[bb] + r;
        if (pos < CAP)
            part[(size_t)bb * CAP + pos] = ((unsigned int)(d & (BUCKET_W - 1)) << 17) | (unsigned int)s;
    }
}

__device__ __forceinline__ void gate_body(char* smem, int gb, int t,
                                          const float* __restrict__ x,
                                          const uint4* __restrict__ gimg,
                                          const float* __restrict__ gate_b,
                                          unsigned short* __restrict__ hpack, int n) {
    uint4* Wl = (uint4*)smem;
    unsigned short* OutS = (unsigned short*)(smem + 32768);
    int lane = t & 63, wv = t >> 6;
    int blockRow = gb * 128;

    for (int idx = t; idx < 2048; idx += 512) Wl[idx] = gimg[idx];

    bf16x8 Ahi[4], Alo[4];
    {
        int arow = blockRow + wv * 16 + (lane & 15);
        const float* ap = x + (size_t)min(arow, n - 1) * 128 + (lane >> 4) * 8;
#pragma unroll
        for (int s = 0; s < 4; s++) {
            float v[8];
            *(float4*)&v[0] = *(const float4*)&ap[s * 32];
            *(float4*)&v[4] = *(const float4*)&ap[s * 32 + 4];
            cvt_hilo8(v, Ahi[s], Alo[s]);
        }
    }
    __syncthreads();

    f32x4 acc[8];
#pragma unroll
    for (int nt = 0; nt < 8; nt++) acc[nt] = (f32x4)(0.f);
#pragma unroll
    for (int s = 0; s < 4; s++) {
        int kb = s * 4 + (lane >> 4);
#pragma unroll
        for (int nt = 0; nt < 8; nt++) {
            int c = nt * 16 + (lane & 15);
            bf16x8 bh = *(bf16x8*)&Wl[c * 16 + (kb ^ (lane & 15))];
            acc[nt] = MF(Ahi[s], bh, acc[nt]);
            acc[nt] = MF(Alo[s], bh, acc[nt]);
        }
    }

    int rl0 = wv * 16 + (lane >> 4) * 4;
#pragma unroll
    for (int nt = 0; nt < 8; nt++) {
        int c = nt * 16 + (lane & 15);
        float gb2 = gate_b[c];
#pragma unroll
        for (int r = 0; r < 4; r++) {
            int grow = min(blockRow + rl0 + r, n - 1);
            float xv = x[(size_t)grow * 128 + c];
            float hv = xv / (1.f + __expf(-(acc[nt][r] + gb2)));
            OutS[(rl0 + r) * OSTRIDE + c] = f2bf(hv);
        }
    }
    __syncthreads();
    {
        int row = t >> 2;
        int c0 = (t & 3) * 32;
        int grow = blockRow + row;
        if (grow < n) {
#pragma unroll
            for (int j = 0; j < 4; j++) {
                uint4 v = *(uint4*)&OutS[row * OSTRIDE + c0 + j * 8];
                *(uint4*)&hpack[(size_t)grow * 128 + c0 + j * 8] = v;
            }
        }
    }
}

__global__ __launch_bounds__(512)
void pg_kernel(const int* __restrict__ src, const int* __restrict__ dst,
               int* __restrict__ bucketCursor, unsigned int* __restrict__ part,
               int E, int NB, int chunk,
               const float* __restrict__ x, const uint4* __restrict__ gimg,
               const float* __restrict__ gate_b, unsigned short* __restrict__ hpack, int n) {
    __shared__ __align__(16) char smem[67584];
    int b = blockIdx.x, t = threadIdx.x;
    if (b < 256) partition_body(smem, b, t, src, dst, bucketCursor, part, E, NB, chunk);
    else         gate_body(smem, b - 256, t, x, gimg, gate_b, hpack, n);
}

// ------------------------------ bucket scan --------------------------------
__global__ __launch_bounds__(512)
void bucket_scan_kernel(const int* __restrict__ bucketCursor,
                        int* __restrict__ bucketBase, int NB) {
    __shared__ int sm[NB_MAX];
    int t = threadIdx.x;
    int v = (t < NB) ? min(bucketCursor[t], CAP) : 0;
    sm[t] = v;
    __syncthreads();
    for (int off = 1; off < NB_MAX; off <<= 1) {
        int a = (t >= off) ? sm[t - off] : 0;
        __syncthreads();
        sm[t] += a;
        __syncthreads();
    }
    if (t < NB) bucketBase[t + 1] = sm[t];
    if (t == 0) bucketBase[0] = 0;
}

// ---------------------- bucket_fill ∪ gemm1 (1 dispatch) --------------------
__device__ __forceinline__ void fill_body(char* smem, int b, int t,
                                          const unsigned int* __restrict__ part,
                                          const int* __restrict__ bucketBase,
                                          int* __restrict__ rowptr, float* __restrict__ dinv,
                                          int* __restrict__ col, int N, int NB) {
    unsigned int* eLDS = (unsigned int*)smem;
    int* deg  = (int*)(smem + CAP * 4);
    int* cur  = deg + BUCKET_W;
    int* wsum = cur + BUCKET_W;   // 8 ints

    int base = bucketBase[b];
    int cnt = bucketBase[b + 1] - base;

    for (int i = t; i < cnt; i += 512) eLDS[i] = part[(size_t)b * CAP + i];
    if (t < 256) deg[t] = 0;
    __syncthreads();
    for (int i = t; i < cnt; i += 512) atomicAdd(&deg[eLDS[i] >> 17], 1);
    __syncthreads();

    int v = (t < 256) ? deg[t] : 0;
    int incl = v;
    int lane = t & 63, w = t >> 6;
    for (int off = 1; off < 64; off <<= 1) {
        int u = __shfl_up(incl, off, 64);
        if (lane >= off) incl += u;
    }
    if (lane == 63) wsum[w] = incl;
    __syncthreads();
    int add = 0;
#pragma unroll
    for (int j = 0; j < 4; j++) if (j < w) add += wsum[j];
    int excl = add + incl - v;
    if (t < 256) {
        cur[t] = excl;
        int gnode = b * BUCKET_W + t;
        if (gnode < N) {
            rowptr[gnode] = base + excl;
            dinv[gnode] = rsqrtf((float)(v + 1));
        }
    }
    if (b == NB - 1 && t == 0) rowptr[N] = base + cnt;
    __syncthreads();

    for (int i = t; i < cnt; i += 512) {
        unsigned int ev = eLDS[i];
        int dl = ev >> 17;
        int p = atomicAdd(&cur[dl], 1);
        col[base + p] = (int)(ev & 0x1FFFFu);
    }
}

// SCALE=1: g = (A@W)*dinv[row]; SCALE=0: g = A@W (dinv never read -> fusable)
template <int SCALE>
__device__ __forceinline__ void gemm_body(char* smem, int gb, int t,
                                          const unsigned short* __restrict__ A,
                                          const uint4* __restrict__ wimg,
                                          const float* __restrict__ dinv,
                                          unsigned short* __restrict__ g, int n) {
    uint4* Wl = (uint4*)smem;
    unsigned short* OutS = (unsigned short*)(smem + 32768);
    int lane = t & 63, wv = t >> 6;
    int blockRow = gb * 128;

    for (int idx = t; idx < 2048; idx += 512) Wl[idx] = wimg[idx];

    bf16x8 Af[4];
    {
        int arow = blockRow + wv * 16 + (lane & 15);
        const uint4* ap = (const uint4*)(A + (size_t)min(arow, n - 1) * 128);
#pragma unroll
        for (int s = 0; s < 4; s++) {
            uint4 u = ap[(lane >> 4) + s * 4];
            Af[s] = *(bf16x8*)&u;
        }
    }
    __syncthreads();

    f32x4 acc[8];
#pragma unroll
    for (int nt = 0; nt < 8; nt++) acc[nt] = (f32x4)(0.f);
#pragma unroll
    for (int s = 0; s < 4; s++) {
        int kb = s * 4 + (lane >> 4);
#pragma unroll
        for (int nt = 0; nt < 8; nt++) {
            int c = nt * 16 + (lane & 15);
            bf16x8 bh = *(bf16x8*)&Wl[c * 16 + (kb ^ (lane & 15))];
            acc[nt] = MF(Af[s], bh, acc[nt]);
        }
    }

    int rl0 = wv * 16 + (lane >> 4) * 4;
    float di[4];
#pragma unroll
    for (int r = 0; r < 4; r++)
        di[r] = SCALE ? dinv[min(blockRow + rl0 + r, n - 1)] : 1.f;
#pragma unroll
    for (int nt = 0; nt < 8; nt++) {
        int c = nt * 16 + (lane & 15);
#pragma unroll
        for (int r = 0; r < 4; r++)
            OutS[(rl0 + r) * OSTRIDE + c] = f2bf(acc[nt][r] * di[r]);
    }
    __syncthreads();
    {
        int row = t >> 2;
        int c0 = (t & 3) * 32;
        int grow = blockRow + row;
        if (grow < n) {
#pragma unroll
            for (int j = 0; j < 4; j++) {
                uint4 v = *(uint4*)&OutS[row * OSTRIDE + c0 + j * 8];
                *(uint4*)&g[(size_t)grow * 128 + c0 + j * 8] = v;
            }
        }
    }
}

__global__ __launch_bounds__(512)
void fg_kernel(const unsigned int* __restrict__ part, const int* __restrict__ bucketBase,
               int* __restrict__ rowptr, float* __restrict__ dinv, int* __restrict__ col,
               int N, int NB,
               const unsigned short* __restrict__ A, const uint4* __restrict__ wimg,
               unsigned short* __restrict__ g) {
    __shared__ __align__(16) char smem[67584];
    int b = blockIdx.x, t = threadIdx.x;
    if (b < NB) fill_body(smem, b, t, part, bucketBase, rowptr, dinv, col, N, NB);
    else        gemm_body<0>(smem, b - NB, t, A, wimg, (const float*)nullptr, g, N);
}

// ----------------------- standalone gemm (W2) ------------------------------
__global__ __launch_bounds__(512)
void gemm_bf16_kernel(const unsigned short* __restrict__ A, const uint4* __restrict__ wimg,
                      const float* __restrict__ dinv, unsigned short* __restrict__ g, int n) {
    __shared__ __align__(16) char smem[67584];
    gemm_body<1>(smem, blockIdx.x, threadIdx.x, A, wimg, dinv, g, n);
}

// ------------------------------ SpMM (bf16 g) ------------------------------
// Feature-split: blocks [0,nhb) do feats [0,64), blocks [nhb,2nhb) do [64,128).
// DVSRC=1: g is unscaled G; weight each message by dinv[src] (and self by dinv[i]).
template <int RELU, int PACK, int DVSRC>
__global__ void spmm_kernel(const uint4* __restrict__ g16, const int* __restrict__ rowptr,
                            const int* __restrict__ col, const float* __restrict__ dinv,
                            const float* __restrict__ bias, void* __restrict__ outv,
                            int n, int nhb) {
    int half = (blockIdx.x >= nhb) ? 1 : 0;
    int rb = blockIdx.x - half * nhb;
    int i = rb * 32 + (threadIdx.x >> 3);
    if (i >= n) return;
    int c = threadIdx.x & 7;

    float di = dinv[i];
    const uint4* gp = g16 + half * 8 + c;
    float acc[8];
    uint4 sv = gp[(size_t)i * 16];
    float wi = DVSRC ? di : 1.f;
    acc[0] = wi * blo(sv.x); acc[1] = wi * bhi(sv.x);
    acc[2] = wi * blo(sv.y); acc[3] = wi * bhi(sv.y);
    acc[4] = wi * blo(sv.z); acc[5] = wi * bhi(sv.z);
    acc[6] = wi * blo(sv.w); acc[7] = wi * bhi(sv.w);

    int e0 = rowptr[i], e1 = rowptr[i + 1];
    int e = e0;
    for (; e + 4 <= e1; e += 4) {
        int s0 = col[e], s1 = col[e + 1], s2 = col[e + 2], s3 = col[e + 3];
        uint4 v0 = gp[(size_t)s0 * 16];
        uint4 v1 = gp[(size_t)s1 * 16];
        uint4 v2 = gp[(size_t)s2 * 16];
        uint4 v3 = gp[(size_t)s3 * 16];
        float w0 = DVSRC ? dinv[s0] : 1.f;
        float w1 = DVSRC ? dinv[s1] : 1.f;
        float w2 = DVSRC ? dinv[s2] : 1.f;
        float w3 = DVSRC ? dinv[s3] : 1.f;
        acc[0] = fmaf(w0, blo(v0.x), fmaf(w1, blo(v1.x), fmaf(w2, blo(v2.x), fmaf(w3, blo(v3.x), acc[0]))));
        acc[1] = fmaf(w0, bhi(v0.x), fmaf(w1, bhi(v1.x), fmaf(w2, bhi(v2.x), fmaf(w3, bhi(v3.x), acc[1]))));
        acc[2] = fmaf(w0, blo(v0.y), fmaf(w1, blo(v1.y), fmaf(w2, blo(v2.y), fmaf(w3, blo(v3.y), acc[2]))));
        acc[3] = fmaf(w0, bhi(v0.y), fmaf(w1, bhi(v1.y), fmaf(w2, bhi(v2.y), fmaf(w3, bhi(v3.y), acc[3]))));
        acc[4] = fmaf(w0, blo(v0.z), fmaf(w1, blo(v1.z), fmaf(w2, blo(v2.z), fmaf(w3, blo(v3.z), acc[4]))));
        acc[5] = fmaf(w0, bhi(v0.z), fmaf(w1, bhi(v1.z), fmaf(w2, bhi(v2.z), fmaf(w3, bhi(v3.z), acc[5]))));
        acc[6] = fmaf(w0, blo(v0.w), fmaf(w1, blo(v1.w), fmaf(w2, blo(v2.w), fmaf(w3, blo(v3.w), acc[6]))));
        acc[7] = fmaf(w0, bhi(v0.w), fmaf(w1, bhi(v1.w), fmaf(w2, bhi(v2.w), fmaf(w3, bhi(v3.w), acc[7]))));
    }
    for (; e < e1; e++) {
        int s0 = col[e];
        uint4 v0 = gp[(size_t)s0 * 16];
        float w0 = DVSRC ? dinv[s0] : 1.f;
        acc[0] = fmaf(w0, blo(v0.x), acc[0]); acc[1] = fmaf(w0, bhi(v0.x), acc[1]);
        acc[2] = fmaf(w0, blo(v0.y), acc[2]); acc[3] = fmaf(w0, bhi(v0.y), acc[3]);
        acc[4] = fmaf(w0, blo(v0.z), acc[4]); acc[5] = fmaf(w0, bhi(v0.z), acc[5]);
        acc[6] = fmaf(w0, blo(v0.w), acc[6]); acc[7] = fmaf(w0, bhi(v0.w), acc[7]);
    }

    const float4* b4 = (const float4*)(bias + half * 64);
    float4 bv0 = b4[c * 2], bv1 = b4[c * 2 + 1];
    float r0[8];
    r0[0] = fmaf(acc[0], di, bv0.x);
    r0[1] = fmaf(acc[1], di, bv0.y);
    r0[2] = fmaf(acc[2], di, bv0.z);
    r0[3] = fmaf(acc[3], di, bv0.w);
    r0[4] = fmaf(acc[4], di, bv1.x);
    r0[5] = fmaf(acc[5], di, bv1.y);
    r0[6] = fmaf(acc[6], di, bv1.z);
    r0[7] = fmaf(acc[7], di, bv1.w);
    if (RELU) {
#pragma unroll
        for (int j = 0; j < 8; j++) r0[j] = fmaxf(r0[j], 0.f);
    }
    if (PACK) {
        uint4 w;
        w.x = (unsigned int)f2bf(r0[0]) | ((unsigned int)f2bf(r0[1]) << 16);
        w.y = (unsigned int)f2bf(r0[2]) | ((unsigned int)f2bf(r0[3]) << 16);
        w.z = (unsigned int)f2bf(r0[4]) | ((unsigned int)f2bf(r0[5]) << 16);
        w.w = (unsigned int)f2bf(r0[6]) | ((unsigned int)f2bf(r0[7]) << 16);
        *(uint4*)((unsigned short*)outv + (size_t)i * 128 + half * 64 + c * 8) = w;
    } else {
        float* o = (float*)outv + (size_t)i * 128 + half * 64 + c * 8;
        f32x4 a = *(f32x4*)&r0[0];
        f32x4 b = *(f32x4*)&r0[4];
        __builtin_nontemporal_store(a, (f32x4*)o);
        __builtin_nontemporal_store(b, (f32x4*)(o + 4));
    }
}

extern "C" void kernel_launch(void* const* d_in, const int* in_sizes, int n_in,
                              void* d_out, int out_size, void* d_ws, size_t ws_size,
                              hipStream_t stream) {
    const float* x      = (const float*)d_in[0];
    const int*   ei     = (const int*)d_in[1];
    const float* gate_W = (const float*)d_in[2];
    const float* gate_b = (const float*)d_in[3];
    const float* W1     = (const float*)d_in[4];
    const float* b1     = (const float*)d_in[5];
    const float* W2     = (const float*)d_in[6];
    const float* b2     = (const float*)d_in[7];
    float* out = (float*)d_out;

    const int N = in_sizes[0] / 128;
    const int E = in_sizes[1] / 2;
    const int* src = ei;
    const int* dst = ei + E;
    const int NB = (N + BUCKET_W - 1) / BUCKET_W;

    char* p = (char*)d_ws;
    auto alloc = [&](size_t bytes) { char* q = p; p += (bytes + 255) & ~(size_t)255; return q; };
    int*   rowptr  = (int*)alloc(((size_t)N + 1) * 4);
    float* dinv    = (float*)alloc((size_t)N * 4);
    int*   colb    = (int*)alloc((size_t)E * 4);
    int*   bcursor = (int*)alloc((size_t)NB * 4);
    int*   bbase   = (int*)alloc(((size_t)NB + 1) * 4);
    uint4* wimg    = (uint4*)alloc((size_t)3 * 2048 * 16);
    unsigned int*   part   = (unsigned int*)alloc((size_t)NB * CAP * 4);
    unsigned short* hpack  = (unsigned short*)alloc((size_t)N * 128 * 2);
    unsigned short* g16    = (unsigned short*)alloc((size_t)N * 128 * 2);
    unsigned short* h1pack = (unsigned short*)alloc((size_t)N * 128 * 2);

    const int pblocks = 256;
    const int chunk = (E + pblocks - 1) / pblocks;
    int gblocks = (N + 127) / 128;
    int nhb = (N + 31) / 32;

    prepinit_kernel<<<13, 512, 0, stream>>>(gate_W, W1, W2, wimg, bcursor, NB);
    pg_kernel<<<256 + gblocks, 512, 0, stream>>>(src, dst, bcursor, part, E, NB, chunk,
                                                 x, wimg, gate_b, hpack, N);
    bucket_scan_kernel<<<1, 512, 0, stream>>>(bcursor, bbase, NB);
    fg_kernel<<<NB + gblocks, 512, 0, stream>>>(part, bbase, rowptr, dinv, colb, N, NB,
                                                hpack, wimg + 2048, g16);
    spmm_kernel<1, 1, 1><<<2 * nhb, 256, 0, stream>>>((const uint4*)g16, rowptr, colb,
                                                      dinv, b1, h1pack, N, nhb);
    gemm_bf16_kernel<<<gblocks, 512, 0, stream>>>(h1pack, wimg + 4096, dinv, g16, N);
    spmm_kernel<0, 0, 0><<<2 * nhb, 256, 0, stream>>>((const uint4*)g16, rowptr, colb,
                                                      dinv, b2, out, N, nhb);
}